// Round 1
// baseline (217.384 us; speedup 1.0000x reference)
//
#include <hip/hip_runtime.h>

#define L_Q 4096
#define D_MODEL 1024
#define N_B 4
#define N_H 8
#define N_P 4
#define M_ROWS (N_B * L_Q)   // 16384

typedef float f32x4 __attribute__((ext_vector_type(4)));
typedef __bf16 bf16x8 __attribute__((ext_vector_type(8)));

__device__ __forceinline__ unsigned short f2bf(float f) {
    unsigned int u = __float_as_uint(f);
    u += 0x7FFFu + ((u >> 16) & 1u);      // round-to-nearest-even
    return (unsigned short)(u >> 16);
}
__device__ __forceinline__ float bf2f(unsigned short s) {
    return __uint_as_float(((unsigned int)s) << 16);
}

// async global->LDS, 16B per lane; LDS dest = wave-uniform base + lane*16
__device__ __forceinline__ void gload_lds16(const void* g, void* l) {
    __builtin_amdgcn_global_load_lds((const __attribute__((address_space(1))) void*)g,
                                     (__attribute__((address_space(3))) void*)l,
                                     16, 0, 0);
}

// ---------------- prep kernels ----------------

__global__ void k_cast_value(const float* __restrict__ in, unsigned short* __restrict__ out, int n4) {
    int i = blockIdx.x * blockDim.x + threadIdx.x;
    const int stride = gridDim.x * blockDim.x;
    for (; i < n4; i += stride) {
        float4 v = ((const float4*)in)[i];
        ushort4 o;
        o.x = f2bf(v.x); o.y = f2bf(v.y); o.z = f2bf(v.z); o.w = f2bf(v.w);
        ((ushort4*)out)[i] = o;
    }
}

__global__ void k_split_query(const float* __restrict__ q, unsigned short* __restrict__ hi,
                              unsigned short* __restrict__ lo, int n4) {
    int i = blockIdx.x * blockDim.x + threadIdx.x;
    const int stride = gridDim.x * blockDim.x;
    for (; i < n4; i += stride) {
        float4 v = ((const float4*)q)[i];
        ushort4 h, l;
        h.x = f2bf(v.x); l.x = f2bf(v.x - bf2f(h.x));
        h.y = f2bf(v.y); l.y = f2bf(v.y - bf2f(h.y));
        h.z = f2bf(v.z); l.z = f2bf(v.z - bf2f(h.z));
        h.w = f2bf(v.w); l.w = f2bf(v.w - bf2f(h.w));
        ((ushort4*)hi)[i] = h;
        ((ushort4*)lo)[i] = l;
    }
}

// WvT/WoT: (N=1024, K=1024) bf16 transposes. WcT: (96, 1024) = [Woff | Wattn]^T, hi/lo split.
__global__ void k_prep_weights(const float* __restrict__ Wv, const float* __restrict__ Wo,
                               const float* __restrict__ Woff, const float* __restrict__ Wattn,
                               unsigned short* __restrict__ WvT, unsigned short* __restrict__ WoT,
                               unsigned short* __restrict__ WcTh, unsigned short* __restrict__ WcTl) {
    const int n1 = D_MODEL * D_MODEL;
    const int n2 = 2 * n1;
    const int n3 = n2 + 96 * D_MODEL;
    int i = blockIdx.x * blockDim.x + threadIdx.x;
    const int stride = gridDim.x * blockDim.x;
    for (; i < n3; i += stride) {
        if (i < n1) {
            int n = i >> 10, k = i & 1023;
            WvT[i] = f2bf(Wv[k * D_MODEL + n]);
        } else if (i < n2) {
            int j = i - n1;
            int n = j >> 10, k = j & 1023;
            WoT[j] = f2bf(Wo[k * D_MODEL + n]);
        } else {
            int j = i - n2;
            int c = j >> 10, k = j & 1023;
            float w = (c < 64) ? Woff[k * 64 + c] : Wattn[k * 32 + (c - 64)];
            unsigned short h = f2bf(w);
            WcTh[j] = h;
            WcTl[j] = f2bf(w - bf2f(h));
        }
    }
}

// ---------------- bf16 MFMA GEMM: C(M,N) = A(M,K) * Bt(N,K)^T + bias ----------------
// 128x128 tile, BK=64, 256 threads (4 waves 2x2), global_load_lds staging (m97 structure).

template <bool OUT_BF16>
__global__ void k_gemm(const unsigned short* __restrict__ A,
                       const unsigned short* __restrict__ Bt,
                       const float* __restrict__ bias,
                       void* __restrict__ Cout,
                       int M, int N, int K) {
    __shared__ unsigned short As[128 * 64];
    __shared__ unsigned short Bs[128 * 64];
    const int tid = threadIdx.x;
    const int w = tid >> 6, lane = tid & 63;
    const int wr = w >> 1, wc = w & 1;
    const int m0 = blockIdx.x * 128, n0 = blockIdx.y * 128;

    f32x4 acc[4][4];
    const f32x4 zero = {0.f, 0.f, 0.f, 0.f};
#pragma unroll
    for (int i = 0; i < 4; ++i)
#pragma unroll
        for (int j = 0; j < 4; ++j) acc[i][j] = zero;

    const int ldrow = lane >> 3;       // 0..7
    const int ke = (lane & 7) * 8;     // k element offset 0..56

    for (int kt = 0; kt < K; kt += 64) {
        __syncthreads();   // previous compute done before LDS overwrite
#pragma unroll
        for (int j = 0; j < 4; ++j) {
            const int ra = w * 32 + j * 8 + ldrow;
            gload_lds16(A + (size_t)(m0 + ra) * K + kt + ke, As + (w * 32 + j * 8) * 64);
            gload_lds16(Bt + (size_t)(n0 + ra) * K + kt + ke, Bs + (w * 32 + j * 8) * 64);
        }
        __syncthreads();   // compiler drains vmcnt before barrier -> LDS tiles ready
#pragma unroll
        for (int kk = 0; kk < 2; ++kk) {
            const int ko = kk * 32 + (lane >> 4) * 8;
            bf16x8 af[4], bfr[4];
#pragma unroll
            for (int i = 0; i < 4; ++i)
                af[i] = *(const bf16x8*)(As + (wr * 64 + i * 16 + (lane & 15)) * 64 + ko);
#pragma unroll
            for (int j = 0; j < 4; ++j)
                bfr[j] = *(const bf16x8*)(Bs + (wc * 64 + j * 16 + (lane & 15)) * 64 + ko);
#pragma unroll
            for (int i = 0; i < 4; ++i)
#pragma unroll
                for (int j = 0; j < 4; ++j)
                    acc[i][j] = __builtin_amdgcn_mfma_f32_16x16x32_bf16(af[i], bfr[j], acc[i][j], 0, 0, 0);
        }
    }

#pragma unroll
    for (int i = 0; i < 4; ++i) {
#pragma unroll
        for (int j = 0; j < 4; ++j) {
            const int col = n0 + wc * 64 + j * 16 + (lane & 15);
            const float bcol = bias[col];
#pragma unroll
            for (int r = 0; r < 4; ++r) {
                const int row = m0 + wr * 64 + i * 16 + (lane >> 4) * 4 + r;
                const float v = acc[i][j][r] + bcol;
                if (OUT_BF16)
                    ((unsigned short*)Cout)[(size_t)row * N + col] = f2bf(v);
                else
                    ((float*)Cout)[(size_t)row * N + col] = v;
            }
        }
    }
}

// ---------------- off/attn projection: C96(M,96) = q @ [Woff|Wattn] + bias ----------------
// fp32-accurate via bf16 hi/lo: q_hi*w_hi + q_hi*w_lo + q_lo*w_hi.
// BM=64, BN=96, BK=64, 256 threads (4 waves: 2 row-halves x 2 col-halves of 48).

__global__ void k_offattn(const unsigned short* __restrict__ qhi,
                          const unsigned short* __restrict__ qlo,
                          const unsigned short* __restrict__ WcTh,
                          const unsigned short* __restrict__ WcTl,
                          const float* __restrict__ boff,
                          const float* __restrict__ battn,
                          float* __restrict__ C96) {
    __shared__ unsigned short As[64 * 64];
    __shared__ unsigned short Bs[96 * 64];
    const int tid = threadIdx.x;
    const int w = tid >> 6, lane = tid & 63;
    const int wr = w >> 1, wc = w & 1;
    const int m0 = blockIdx.x * 64;

    f32x4 acc[2][3];
    const f32x4 zero = {0.f, 0.f, 0.f, 0.f};
#pragma unroll
    for (int i = 0; i < 2; ++i)
#pragma unroll
        for (int j = 0; j < 3; ++j) acc[i][j] = zero;

    const int ldrow = lane >> 3;
    const int ke = (lane & 7) * 8;

    for (int term = 0; term < 3; ++term) {
        const unsigned short* Ag = (term == 2) ? qlo : qhi;
        const unsigned short* Bg = (term == 1) ? WcTl : WcTh;
        for (int kt = 0; kt < D_MODEL; kt += 64) {
            __syncthreads();
            // A tile: 64 rows, wave w stages rows [w*16, w*16+16)
#pragma unroll
            for (int j = 0; j < 2; ++j) {
                const int ra = w * 16 + j * 8 + ldrow;
                gload_lds16(Ag + (size_t)(m0 + ra) * D_MODEL + kt + ke, As + (w * 16 + j * 8) * 64);
            }
            // B tile: 96 rows, waves 0..2 stage 32 rows each
            if (w < 3) {
#pragma unroll
                for (int j = 0; j < 4; ++j) {
                    const int rb = w * 32 + j * 8 + ldrow;
                    gload_lds16(Bg + (size_t)rb * D_MODEL + kt + ke, Bs + (w * 32 + j * 8) * 64);
                }
            }
            __syncthreads();
#pragma unroll
            for (int kk = 0; kk < 2; ++kk) {
                const int ko = kk * 32 + (lane >> 4) * 8;
                bf16x8 af[2], bfr[3];
#pragma unroll
                for (int i = 0; i < 2; ++i)
                    af[i] = *(const bf16x8*)(As + (wr * 32 + i * 16 + (lane & 15)) * 64 + ko);
#pragma unroll
                for (int j = 0; j < 3; ++j)
                    bfr[j] = *(const bf16x8*)(Bs + (wc * 48 + j * 16 + (lane & 15)) * 64 + ko);
#pragma unroll
                for (int i = 0; i < 2; ++i)
#pragma unroll
                    for (int j = 0; j < 3; ++j)
                        acc[i][j] = __builtin_amdgcn_mfma_f32_16x16x32_bf16(af[i], bfr[j], acc[i][j], 0, 0, 0);
            }
        }
    }

#pragma unroll
    for (int i = 0; i < 2; ++i) {
#pragma unroll
        for (int j = 0; j < 3; ++j) {
            const int col = wc * 48 + j * 16 + (lane & 15);
            const float bcol = (col < 64) ? boff[col] : battn[col - 64];
#pragma unroll
            for (int r = 0; r < 4; ++r) {
                const int row = m0 + wr * 32 + i * 16 + (lane >> 4) * 4 + r;
                C96[(size_t)row * 96 + col] = acc[i][j][r] + bcol;
            }
        }
    }
}

// ---------------- sampler: softmax + bilinear gather + weighted sum ----------------
// one block per (b,l) row; 32 threads per head, 4 channels per thread.

__global__ void k_sampler(const float* __restrict__ C96,
                          const unsigned short* __restrict__ vproj,
                          unsigned short* __restrict__ agg) {
    const int row = blockIdx.x;          // b*L + l
    const int b = row >> 12;
    const int l = row & (L_Q - 1);
    const int t = threadIdx.x;

    __shared__ float cv[96];
    if (t < 96) cv[t] = C96[(size_t)row * 96 + t];
    __syncthreads();

    const int h = t >> 5;
    const int dd = (t & 31) * 4;
    const float ref_y = (float)l / 4095.0f;

    float lg[4];
#pragma unroll
    for (int p = 0; p < 4; ++p) lg[p] = cv[64 + h * 4 + p];
    const float mx = fmaxf(fmaxf(lg[0], lg[1]), fmaxf(lg[2], lg[3]));
    float ex[4];
    float es = 0.f;
#pragma unroll
    for (int p = 0; p < 4; ++p) { ex[p] = expf(lg[p] - mx); es += ex[p]; }
    const float inv = 1.0f / es;

    float acc0 = 0.f, acc1 = 0.f, acc2 = 0.f, acc3 = 0.f;
#pragma unroll
    for (int p = 0; p < 4; ++p) {
        const float ox = cv[h * 8 + p * 2];
        const float oy = cv[h * 8 + p * 2 + 1];
        const float lx = fminf(fmaxf(ox, 0.0f), 1.0f);               // ref_x = 0
        const float ly = fminf(fmaxf(ref_y + oy, 0.0f), 1.0f);
        const float ux = (lx + 1.0f) * 2048.0f - 0.5f;               // ((x+1)*L - 1)/2
        const float wy = 1.0f - ly * 0.5f;                           // uy in [0,0.5] -> wy = 1-uy
        const float x0f = floorf(ux);
        const int i0 = (int)x0f;
        const int i1 = i0 + 1;
        const float w1 = ux - x0f;
        const float w0 = 1.0f - w1;
        const float aw = ex[p] * inv * wy;
        const float f0 = aw * w0 * ((i0 >= 0 && i0 < L_Q) ? 1.0f : 0.0f);
        const float f1 = aw * w1 * ((i1 >= 0 && i1 < L_Q) ? 1.0f : 0.0f);
        const int i0c = i0 < 0 ? 0 : (i0 > L_Q - 1 ? L_Q - 1 : i0);
        const int i1c = i1 < 0 ? 0 : (i1 > L_Q - 1 ? L_Q - 1 : i1);
        const ushort4 v0 = *(const ushort4*)(vproj + (size_t)(b * L_Q + i0c) * D_MODEL + h * 128 + dd);
        const ushort4 v1 = *(const ushort4*)(vproj + (size_t)(b * L_Q + i1c) * D_MODEL + h * 128 + dd);
        acc0 += f0 * bf2f(v0.x) + f1 * bf2f(v1.x);
        acc1 += f0 * bf2f(v0.y) + f1 * bf2f(v1.y);
        acc2 += f0 * bf2f(v0.z) + f1 * bf2f(v1.z);
        acc3 += f0 * bf2f(v0.w) + f1 * bf2f(v1.w);
    }
    ushort4 o;
    o.x = f2bf(acc0); o.y = f2bf(acc1); o.z = f2bf(acc2); o.w = f2bf(acc3);
    *(ushort4*)(agg + (size_t)row * D_MODEL + t * 4) = o;
}

// ---------------- launch ----------------

extern "C" void kernel_launch(void* const* d_in, const int* in_sizes, int n_in,
                              void* d_out, int out_size, void* d_ws, size_t ws_size,
                              hipStream_t stream) {
    const float* query = (const float*)d_in[0];
    // d_in[1] key_in: unused (dead code in reference)
    const float* value = (const float*)d_in[2];
    // d_in[3] Wqk, d_in[4] bqk: unused (dead code)
    const float* Wv    = (const float*)d_in[5];
    const float* bv    = (const float*)d_in[6];
    const float* Woff  = (const float*)d_in[7];
    const float* boff  = (const float*)d_in[8];
    const float* Wattn = (const float*)d_in[9];
    const float* battn = (const float*)d_in[10];
    const float* Wo    = (const float*)d_in[11];
    const float* bo    = (const float*)d_in[12];

    char* ws = (char*)d_ws;
    size_t off = 0;
    auto alloc = [&](size_t bytes) -> char* {
        char* p = ws + off;
        off += (bytes + 255) & ~(size_t)255;
        return p;
    };
    unsigned short* val_bf = (unsigned short*)alloc((size_t)M_ROWS * D_MODEL * 2);  // 32MB
    unsigned short* qhi    = (unsigned short*)alloc((size_t)M_ROWS * D_MODEL * 2);  // 32MB
    unsigned short* qlo    = (unsigned short*)alloc((size_t)M_ROWS * D_MODEL * 2);  // 32MB
    unsigned short* vproj  = (unsigned short*)alloc((size_t)M_ROWS * D_MODEL * 2);  // 32MB
    unsigned short* agg    = (unsigned short*)alloc((size_t)M_ROWS * D_MODEL * 2);  // 32MB
    float*          C96    = (float*)alloc((size_t)M_ROWS * 96 * 4);                // 6MB
    unsigned short* WvT    = (unsigned short*)alloc((size_t)D_MODEL * D_MODEL * 2); // 2MB
    unsigned short* WoT    = (unsigned short*)alloc((size_t)D_MODEL * D_MODEL * 2); // 2MB
    unsigned short* WcTh   = (unsigned short*)alloc((size_t)96 * D_MODEL * 2);
    unsigned short* WcTl   = (unsigned short*)alloc((size_t)96 * D_MODEL * 2);

    const int n4 = M_ROWS * D_MODEL / 4;
    k_cast_value<<<2048, 256, 0, stream>>>(value, val_bf, n4);
    k_split_query<<<2048, 256, 0, stream>>>(query, qhi, qlo, n4);
    k_prep_weights<<<1024, 256, 0, stream>>>(Wv, Wo, Woff, Wattn, WvT, WoT, WcTh, WcTl);

    // v = value @ Wv + bv   (bf16 out)
    k_gemm<true><<<dim3(M_ROWS / 128, D_MODEL / 128), 256, 0, stream>>>(
        val_bf, WvT, bv, vproj, M_ROWS, D_MODEL, D_MODEL);

    // C96 = query @ [Woff|Wattn] + [boff|battn]   (fp32-accurate hi/lo)
    k_offattn<<<M_ROWS / 64, 256, 0, stream>>>(qhi, qlo, WcTh, WcTl, boff, battn, C96);

    // agg = deformable sample + attn-weighted sum  (bf16 out)
    k_sampler<<<M_ROWS, 256, 0, stream>>>(C96, vproj, agg);

    // out = agg @ Wo + bo   (f32 out)
    k_gemm<false><<<dim3(M_ROWS / 128, D_MODEL / 128), 256, 0, stream>>>(
        agg, WoT, bo, (float*)d_out, M_ROWS, D_MODEL, D_MODEL);
}

// Round 2
// 209.563 us; speedup vs baseline: 1.0373x; 1.0373x over previous
//
#include <hip/hip_runtime.h>

#define L_Q 4096
#define D_MODEL 1024
#define N_B 4
#define N_H 8
#define N_P 4
#define M_ROWS (N_B * L_Q)   // 16384

typedef float f32x4 __attribute__((ext_vector_type(4)));
typedef __bf16 bf16x8 __attribute__((ext_vector_type(8)));

__device__ __forceinline__ unsigned short f2bf(float f) {
    unsigned int u = __float_as_uint(f);
    u += 0x7FFFu + ((u >> 16) & 1u);      // round-to-nearest-even
    return (unsigned short)(u >> 16);
}
__device__ __forceinline__ float bf2f(unsigned short s) {
    return __uint_as_float(((unsigned int)s) << 16);
}

// async global->LDS, 16B per lane; LDS dest = wave-uniform base + lane*16
__device__ __forceinline__ void gload_lds16(const void* g, void* l) {
    __builtin_amdgcn_global_load_lds((const __attribute__((address_space(1))) void*)g,
                                     (__attribute__((address_space(3))) void*)l,
                                     16, 0, 0);
}

template <int N> __device__ __forceinline__ void wait_vmcnt() {
    if constexpr (N == 12)     asm volatile("s_waitcnt vmcnt(12)" ::: "memory");
    else if constexpr (N == 8) asm volatile("s_waitcnt vmcnt(8)"  ::: "memory");
    else if constexpr (N == 4) asm volatile("s_waitcnt vmcnt(4)"  ::: "memory");
    else                       asm volatile("s_waitcnt vmcnt(0)"  ::: "memory");
}

// ---------------- prep kernels ----------------

__global__ void k_cast_value(const float* __restrict__ in, unsigned short* __restrict__ out, int n4) {
    int i = blockIdx.x * blockDim.x + threadIdx.x;
    const int stride = gridDim.x * blockDim.x;
    for (; i < n4; i += stride) {
        float4 v = ((const float4*)in)[i];
        ushort4 o;
        o.x = f2bf(v.x); o.y = f2bf(v.y); o.z = f2bf(v.z); o.w = f2bf(v.w);
        ((ushort4*)out)[i] = o;
    }
}

__global__ void k_split_query(const float* __restrict__ q, unsigned short* __restrict__ hi,
                              unsigned short* __restrict__ lo, int n4) {
    int i = blockIdx.x * blockDim.x + threadIdx.x;
    const int stride = gridDim.x * blockDim.x;
    for (; i < n4; i += stride) {
        float4 v = ((const float4*)q)[i];
        ushort4 h, l;
        h.x = f2bf(v.x); l.x = f2bf(v.x - bf2f(h.x));
        h.y = f2bf(v.y); l.y = f2bf(v.y - bf2f(h.y));
        h.z = f2bf(v.z); l.z = f2bf(v.z - bf2f(h.z));
        h.w = f2bf(v.w); l.w = f2bf(v.w - bf2f(h.w));
        ((ushort4*)hi)[i] = h;
        ((ushort4*)lo)[i] = l;
    }
}

// WvT/WoT: (N=1024, K=1024) bf16 transposes. WcT: (96, 1024) = [Woff | Wattn]^T, hi/lo split.
__global__ void k_prep_weights(const float* __restrict__ Wv, const float* __restrict__ Wo,
                               const float* __restrict__ Woff, const float* __restrict__ Wattn,
                               unsigned short* __restrict__ WvT, unsigned short* __restrict__ WoT,
                               unsigned short* __restrict__ WcTh, unsigned short* __restrict__ WcTl) {
    const int n1 = D_MODEL * D_MODEL;
    const int n2 = 2 * n1;
    const int n3 = n2 + 96 * D_MODEL;
    int i = blockIdx.x * blockDim.x + threadIdx.x;
    const int stride = gridDim.x * blockDim.x;
    for (; i < n3; i += stride) {
        if (i < n1) {
            int n = i >> 10, k = i & 1023;
            WvT[i] = f2bf(Wv[k * D_MODEL + n]);
        } else if (i < n2) {
            int j = i - n1;
            int n = j >> 10, k = j & 1023;
            WoT[j] = f2bf(Wo[k * D_MODEL + n]);
        } else {
            int j = i - n2;
            int c = j >> 10, k = j & 1023;
            float w = (c < 64) ? Woff[k * 64 + c] : Wattn[k * 32 + (c - 64)];
            unsigned short h = f2bf(w);
            WcTh[j] = h;
            WcTl[j] = f2bf(w - bf2f(h));
        }
    }
}

// ---------------- 256x256 pipelined bf16 MFMA GEMM: C = A(M,K) * Bt(N,K)^T + bias ----------------
// M=16384, N=K=1024 fixed. 512 threads = 8 waves (2M x 4N), per-wave C = 128x64.
// K in 32-wide slices; ring of 4 LDS slices; counted vmcnt(12) pipeline (T3+T4),
// XOR-swizzled LDS (T2) via pre-swizzled global source, setprio around MFMA (T5).

template <bool OUT_BF16>
__global__ __launch_bounds__(512, 2) void k_gemm256(const unsigned short* __restrict__ A,
                                                    const unsigned short* __restrict__ Bt,
                                                    const float* __restrict__ bias,
                                                    void* __restrict__ Cout) {
    __shared__ __align__(16) unsigned short lds[4][2][8192];   // 4 slices x {A,B} x 256rows x 32k
    const int tid = threadIdx.x;
    const int w = tid >> 6, lane = tid & 63;
    const int wm = w >> 2, wn = w & 3;

    // XCD-bijective swizzle: 256 blocks = 64(M) x 4(N)
    const int bid = blockIdx.x;
    const int swz = (bid & 7) * 32 + (bid >> 3);
    const int m0 = (swz >> 2) * 256;
    const int n0 = (swz & 3) * 256;

    // staging: per-slice unit = 256 rows x 32 k (16KB) per matrix, 2 issues (j=0: rows 0-127, j=1: 128-255)
    // LDS linear dest row = j*128 + w*16 + lane/4, chunk(16B) = lane&3.
    // Inverse-swizzle source so that ds_read with col^=(row>>1)&3 sees the right data.
    const int lr = lane >> 2;
    const int lc = (lane & 3) ^ ((lane >> 3) & 3);
    const unsigned short* gA0 = A  + (size_t)(m0 + w * 16 + lr) * D_MODEL + lc * 8;
    const unsigned short* gA1 = gA0 + (size_t)128 * D_MODEL;
    const unsigned short* gB0 = Bt + (size_t)(n0 + w * 16 + lr) * D_MODEL + lc * 8;
    const unsigned short* gB1 = gB0 + (size_t)128 * D_MODEL;

    // prologue: stage slices 0..2 into slots 0..2
    for (int t = 0; t < 3; ++t) {
        gload_lds16(gA0 + t * 32, &lds[t][0][w * 512]);
        gload_lds16(gA1 + t * 32, &lds[t][0][4096 + w * 512]);
        gload_lds16(gB0 + t * 32, &lds[t][1][w * 512]);
        gload_lds16(gB1 + t * 32, &lds[t][1][4096 + w * 512]);
    }
    gA0 += 96; gA1 += 96; gB0 += 96; gB1 += 96;

    f32x4 acc[8][4];
    const f32x4 zero = {0.f, 0.f, 0.f, 0.f};
#pragma unroll
    for (int i = 0; i < 8; ++i)
#pragma unroll
        for (int j = 0; j < 4; ++j) acc[i][j] = zero;

    const int fr = lane & 15;
    const int kq = lane >> 4;
    const int c2 = kq ^ ((lane >> 1) & 3);    // swizzled 16B chunk for ds_read

#define GPHASE(S_, ST_, VM_) do {                                                      \
        if (ST_) {                                                                     \
            const int slot3_ = ((S_) + 3) & 3;                                         \
            gload_lds16(gA0, &lds[slot3_][0][w * 512]);                                \
            gload_lds16(gA1, &lds[slot3_][0][4096 + w * 512]);                         \
            gload_lds16(gB0, &lds[slot3_][1][w * 512]);                                \
            gload_lds16(gB1, &lds[slot3_][1][4096 + w * 512]);                         \
            gA0 += 32; gA1 += 32; gB0 += 32; gB1 += 32;                                \
        }                                                                              \
        wait_vmcnt<VM_>();                                                             \
        __builtin_amdgcn_s_barrier();                                                  \
        asm volatile("" ::: "memory");                                                 \
        const unsigned short* As_ = &lds[(S_) & 3][0][0];                              \
        const unsigned short* Bs_ = &lds[(S_) & 3][1][0];                              \
        bf16x8 af[8], bfv[4];                                                          \
        _Pragma("unroll") for (int i = 0; i < 8; ++i)                                  \
            af[i] = *(const bf16x8*)(As_ + (wm * 128 + i * 16 + fr) * 32 + c2 * 8);    \
        _Pragma("unroll") for (int j = 0; j < 4; ++j)                                  \
            bfv[j] = *(const bf16x8*)(Bs_ + (wn * 64 + j * 16 + fr) * 32 + c2 * 8);    \
        __builtin_amdgcn_s_setprio(1);                                                 \
        _Pragma("unroll") for (int i = 0; i < 8; ++i)                                  \
            _Pragma("unroll") for (int j = 0; j < 4; ++j)                              \
                acc[i][j] = __builtin_amdgcn_mfma_f32_16x16x32_bf16(af[i], bfv[j], acc[i][j], 0, 0, 0); \
        __builtin_amdgcn_s_setprio(0);                                                 \
        asm volatile("s_waitcnt lgkmcnt(0)" ::: "memory");                             \
        __builtin_amdgcn_s_barrier();                                                  \
        asm volatile("" ::: "memory");                                                 \
    } while (0)

    for (int s = 0; s < 29; ++s) GPHASE(s, true, 12);
    GPHASE(29, false, 8);
    GPHASE(30, false, 4);
    GPHASE(31, false, 0);
#undef GPHASE

#pragma unroll
    for (int i = 0; i < 8; ++i) {
#pragma unroll
        for (int j = 0; j < 4; ++j) {
            const int col = n0 + wn * 64 + j * 16 + fr;
            const float bcol = bias[col];
#pragma unroll
            for (int r = 0; r < 4; ++r) {
                const int row = m0 + wm * 128 + i * 16 + kq * 4 + r;
                const float v = acc[i][j][r] + bcol;
                if (OUT_BF16)
                    ((unsigned short*)Cout)[(size_t)row * D_MODEL + col] = f2bf(v);
                else
                    ((float*)Cout)[(size_t)row * D_MODEL + col] = v;
            }
        }
    }
}

// ---------------- off/attn projection: C96(M,96) = q @ [Woff|Wattn] + bias ----------------
// fp32-accurate via bf16 hi/lo: q_hi*w_hi + q_hi*w_lo + q_lo*w_hi.

__global__ void k_offattn(const unsigned short* __restrict__ qhi,
                          const unsigned short* __restrict__ qlo,
                          const unsigned short* __restrict__ WcTh,
                          const unsigned short* __restrict__ WcTl,
                          const float* __restrict__ boff,
                          const float* __restrict__ battn,
                          float* __restrict__ C96) {
    __shared__ unsigned short As[64 * 64];
    __shared__ unsigned short Bs[96 * 64];
    const int tid = threadIdx.x;
    const int w = tid >> 6, lane = tid & 63;
    const int wr = w >> 1, wc = w & 1;
    const int m0 = blockIdx.x * 64;

    f32x4 acc[2][3];
    const f32x4 zero = {0.f, 0.f, 0.f, 0.f};
#pragma unroll
    for (int i = 0; i < 2; ++i)
#pragma unroll
        for (int j = 0; j < 3; ++j) acc[i][j] = zero;

    const int ldrow = lane >> 3;
    const int ke = (lane & 7) * 8;

    for (int term = 0; term < 3; ++term) {
        const unsigned short* Ag = (term == 2) ? qlo : qhi;
        const unsigned short* Bg = (term == 1) ? WcTl : WcTh;
        for (int kt = 0; kt < D_MODEL; kt += 64) {
            __syncthreads();
#pragma unroll
            for (int j = 0; j < 2; ++j) {
                const int ra = w * 16 + j * 8 + ldrow;
                gload_lds16(Ag + (size_t)(m0 + ra) * D_MODEL + kt + ke, As + (w * 16 + j * 8) * 64);
            }
            if (w < 3) {
#pragma unroll
                for (int j = 0; j < 4; ++j) {
                    const int rb = w * 32 + j * 8 + ldrow;
                    gload_lds16(Bg + (size_t)rb * D_MODEL + kt + ke, Bs + (w * 32 + j * 8) * 64);
                }
            }
            __syncthreads();
#pragma unroll
            for (int kk = 0; kk < 2; ++kk) {
                const int ko = kk * 32 + (lane >> 4) * 8;
                bf16x8 af[2], bfr[3];
#pragma unroll
                for (int i = 0; i < 2; ++i)
                    af[i] = *(const bf16x8*)(As + (wr * 32 + i * 16 + (lane & 15)) * 64 + ko);
#pragma unroll
                for (int j = 0; j < 3; ++j)
                    bfr[j] = *(const bf16x8*)(Bs + (wc * 48 + j * 16 + (lane & 15)) * 64 + ko);
#pragma unroll
                for (int i = 0; i < 2; ++i)
#pragma unroll
                    for (int j = 0; j < 3; ++j)
                        acc[i][j] = __builtin_amdgcn_mfma_f32_16x16x32_bf16(af[i], bfr[j], acc[i][j], 0, 0, 0);
            }
        }
    }

#pragma unroll
    for (int i = 0; i < 2; ++i) {
#pragma unroll
        for (int j = 0; j < 3; ++j) {
            const int col = wc * 48 + j * 16 + (lane & 15);
            const float bcol = (col < 64) ? boff[col] : battn[col - 64];
#pragma unroll
            for (int r = 0; r < 4; ++r) {
                const int row = m0 + wr * 32 + i * 16 + (lane >> 4) * 4 + r;
                C96[(size_t)row * 96 + col] = acc[i][j][r] + bcol;
            }
        }
    }
}

// ---------------- sampler: softmax + bilinear gather + weighted sum ----------------

__global__ void k_sampler(const float* __restrict__ C96,
                          const unsigned short* __restrict__ vproj,
                          unsigned short* __restrict__ agg) {
    const int row = blockIdx.x;          // b*L + l
    const int b = row >> 12;
    const int l = row & (L_Q - 1);
    const int t = threadIdx.x;

    __shared__ float cv[96];
    if (t < 96) cv[t] = C96[(size_t)row * 96 + t];
    __syncthreads();

    const int h = t >> 5;
    const int dd = (t & 31) * 4;
    const float ref_y = (float)l / 4095.0f;

    float lg[4];
#pragma unroll
    for (int p = 0; p < 4; ++p) lg[p] = cv[64 + h * 4 + p];
    const float mx = fmaxf(fmaxf(lg[0], lg[1]), fmaxf(lg[2], lg[3]));
    float ex[4];
    float es = 0.f;
#pragma unroll
    for (int p = 0; p < 4; ++p) { ex[p] = expf(lg[p] - mx); es += ex[p]; }
    const float inv = 1.0f / es;

    float acc0 = 0.f, acc1 = 0.f, acc2 = 0.f, acc3 = 0.f;
#pragma unroll
    for (int p = 0; p < 4; ++p) {
        const float ox = cv[h * 8 + p * 2];
        const float oy = cv[h * 8 + p * 2 + 1];
        const float lx = fminf(fmaxf(ox, 0.0f), 1.0f);               // ref_x = 0
        const float ly = fminf(fmaxf(ref_y + oy, 0.0f), 1.0f);
        const float ux = (lx + 1.0f) * 2048.0f - 0.5f;               // ((x+1)*L - 1)/2
        const float wy = 1.0f - ly * 0.5f;                           // uy in [0,0.5] -> wy = 1-uy
        const float x0f = floorf(ux);
        const int i0 = (int)x0f;
        const int i1 = i0 + 1;
        const float w1 = ux - x0f;
        const float w0 = 1.0f - w1;
        const float aw = ex[p] * inv * wy;
        const float f0 = aw * w0 * ((i0 >= 0 && i0 < L_Q) ? 1.0f : 0.0f);
        const float f1 = aw * w1 * ((i1 >= 0 && i1 < L_Q) ? 1.0f : 0.0f);
        const int i0c = i0 < 0 ? 0 : (i0 > L_Q - 1 ? L_Q - 1 : i0);
        const int i1c = i1 < 0 ? 0 : (i1 > L_Q - 1 ? L_Q - 1 : i1);
        const ushort4 v0 = *(const ushort4*)(vproj + (size_t)(b * L_Q + i0c) * D_MODEL + h * 128 + dd);
        const ushort4 v1 = *(const ushort4*)(vproj + (size_t)(b * L_Q + i1c) * D_MODEL + h * 128 + dd);
        acc0 += f0 * bf2f(v0.x) + f1 * bf2f(v1.x);
        acc1 += f0 * bf2f(v0.y) + f1 * bf2f(v1.y);
        acc2 += f0 * bf2f(v0.z) + f1 * bf2f(v1.z);
        acc3 += f0 * bf2f(v0.w) + f1 * bf2f(v1.w);
    }
    ushort4 o;
    o.x = f2bf(acc0); o.y = f2bf(acc1); o.z = f2bf(acc2); o.w = f2bf(acc3);
    *(ushort4*)(agg + (size_t)row * D_MODEL + t * 4) = o;
}

// ---------------- launch ----------------

extern "C" void kernel_launch(void* const* d_in, const int* in_sizes, int n_in,
                              void* d_out, int out_size, void* d_ws, size_t ws_size,
                              hipStream_t stream) {
    const float* query = (const float*)d_in[0];
    // d_in[1] key_in: unused (dead code in reference)
    const float* value = (const float*)d_in[2];
    // d_in[3] Wqk, d_in[4] bqk: unused (dead code)
    const float* Wv    = (const float*)d_in[5];
    const float* bv    = (const float*)d_in[6];
    const float* Woff  = (const float*)d_in[7];
    const float* boff  = (const float*)d_in[8];
    const float* Wattn = (const float*)d_in[9];
    const float* battn = (const float*)d_in[10];
    const float* Wo    = (const float*)d_in[11];
    const float* bo    = (const float*)d_in[12];

    char* ws = (char*)d_ws;
    size_t off = 0;
    auto alloc = [&](size_t bytes) -> char* {
        char* p = ws + off;
        off += (bytes + 255) & ~(size_t)255;
        return p;
    };
    unsigned short* val_bf = (unsigned short*)alloc((size_t)M_ROWS * D_MODEL * 2);  // 32MB
    unsigned short* qhi    = (unsigned short*)alloc((size_t)M_ROWS * D_MODEL * 2);  // 32MB
    unsigned short* qlo    = (unsigned short*)alloc((size_t)M_ROWS * D_MODEL * 2);  // 32MB
    unsigned short* vproj  = (unsigned short*)alloc((size_t)M_ROWS * D_MODEL * 2);  // 32MB
    unsigned short* agg    = (unsigned short*)alloc((size_t)M_ROWS * D_MODEL * 2);  // 32MB
    float*          C96    = (float*)alloc((size_t)M_ROWS * 96 * 4);                // 6MB
    unsigned short* WvT    = (unsigned short*)alloc((size_t)D_MODEL * D_MODEL * 2); // 2MB
    unsigned short* WoT    = (unsigned short*)alloc((size_t)D_MODEL * D_MODEL * 2); // 2MB
    unsigned short* WcTh   = (unsigned short*)alloc((size_t)96 * D_MODEL * 2);
    unsigned short* WcTl   = (unsigned short*)alloc((size_t)96 * D_MODEL * 2);

    const int n4 = M_ROWS * D_MODEL / 4;
    k_cast_value<<<2048, 256, 0, stream>>>(value, val_bf, n4);
    k_split_query<<<2048, 256, 0, stream>>>(query, qhi, qlo, n4);
    k_prep_weights<<<1024, 256, 0, stream>>>(Wv, Wo, Woff, Wattn, WvT, WoT, WcTh, WcTl);

    // v = value @ Wv + bv   (bf16 out)
    k_gemm256<true><<<256, 512, 0, stream>>>(val_bf, WvT, bv, vproj);

    // C96 = query @ [Woff|Wattn] + [boff|battn]   (fp32-accurate hi/lo)
    k_offattn<<<M_ROWS / 64, 256, 0, stream>>>(qhi, qlo, WcTh, WcTl, boff, battn, C96);

    // agg = deformable sample + attn-weighted sum  (bf16 out)
    k_sampler<<<M_ROWS, 256, 0, stream>>>(C96, vproj, agg);

    // out = agg @ Wo + bo   (f32 out)
    k_gemm256<false><<<256, 512, 0, stream>>>(agg, WoT, bo, (float*)d_out);
}

// Round 3
// 198.805 us; speedup vs baseline: 1.0934x; 1.0541x over previous
//
#include <hip/hip_runtime.h>

#define L_Q 4096
#define D_MODEL 1024
#define N_B 4
#define N_H 8
#define N_P 4
#define M_ROWS (N_B * L_Q)   // 16384

typedef float f32x4 __attribute__((ext_vector_type(4)));
typedef __bf16 bf16x8 __attribute__((ext_vector_type(8)));

__device__ __forceinline__ unsigned short f2bf(float f) {
    unsigned int u = __float_as_uint(f);
    u += 0x7FFFu + ((u >> 16) & 1u);      // round-to-nearest-even
    return (unsigned short)(u >> 16);
}
__device__ __forceinline__ float bf2f(unsigned short s) {
    return __uint_as_float(((unsigned int)s) << 16);
}

// async global->LDS, 16B per lane; LDS dest = wave-uniform base + lane*16
__device__ __forceinline__ void gload_lds16(const void* g, void* l) {
    __builtin_amdgcn_global_load_lds((const __attribute__((address_space(1))) void*)g,
                                     (__attribute__((address_space(3))) void*)l,
                                     16, 0, 0);
}

template <int N> __device__ __forceinline__ void wait_vmcnt() {
    if constexpr (N == 6)      asm volatile("s_waitcnt vmcnt(6)"  ::: "memory");
    else                       asm volatile("s_waitcnt vmcnt(0)"  ::: "memory");
}

// ---------------- prep kernels ----------------

__global__ void k_cast_value(const float* __restrict__ in, unsigned short* __restrict__ out, int n4) {
    int i = blockIdx.x * blockDim.x + threadIdx.x;
    const int stride = gridDim.x * blockDim.x;
    for (; i < n4; i += stride) {
        float4 v = ((const float4*)in)[i];
        ushort4 o;
        o.x = f2bf(v.x); o.y = f2bf(v.y); o.z = f2bf(v.z); o.w = f2bf(v.w);
        ((ushort4*)out)[i] = o;
    }
}

__global__ void k_split_query(const float* __restrict__ q, unsigned short* __restrict__ hi,
                              unsigned short* __restrict__ lo, int n4) {
    int i = blockIdx.x * blockDim.x + threadIdx.x;
    const int stride = gridDim.x * blockDim.x;
    for (; i < n4; i += stride) {
        float4 v = ((const float4*)q)[i];
        ushort4 h, l;
        h.x = f2bf(v.x); l.x = f2bf(v.x - bf2f(h.x));
        h.y = f2bf(v.y); l.y = f2bf(v.y - bf2f(h.y));
        h.z = f2bf(v.z); l.z = f2bf(v.z - bf2f(h.z));
        h.w = f2bf(v.w); l.w = f2bf(v.w - bf2f(h.w));
        ((ushort4*)hi)[i] = h;
        ((ushort4*)lo)[i] = l;
    }
}

// WvT/WoT: (N=1024, K=1024) bf16 transposes. WcT: (96, 1024) = [Woff | Wattn]^T, hi/lo split.
__global__ void k_prep_weights(const float* __restrict__ Wv, const float* __restrict__ Wo,
                               const float* __restrict__ Woff, const float* __restrict__ Wattn,
                               unsigned short* __restrict__ WvT, unsigned short* __restrict__ WoT,
                               unsigned short* __restrict__ WcTh, unsigned short* __restrict__ WcTl) {
    const int n1 = D_MODEL * D_MODEL;
    const int n2 = 2 * n1;
    const int n3 = n2 + 96 * D_MODEL;
    int i = blockIdx.x * blockDim.x + threadIdx.x;
    const int stride = gridDim.x * blockDim.x;
    for (; i < n3; i += stride) {
        if (i < n1) {
            int n = i >> 10, k = i & 1023;
            WvT[i] = f2bf(Wv[k * D_MODEL + n]);
        } else if (i < n2) {
            int j = i - n1;
            int n = j >> 10, k = j & 1023;
            WoT[j] = f2bf(Wo[k * D_MODEL + n]);
        } else {
            int j = i - n2;
            int c = j >> 10, k = j & 1023;
            float w = (c < 64) ? Woff[k * 64 + c] : Wattn[k * 32 + (c - 64)];
            unsigned short h = f2bf(w);
            WcTh[j] = h;
            WcTl[j] = f2bf(w - bf2f(h));
        }
    }
}

// ---------------- 256x256 8-phase bf16 MFMA GEMM (m201 template): C = A(M,K)*Bt(N,K)^T + bias ----
// M=16384, N=K=1024. 512 threads = 8 waves (2M x 4N), per-wave C = 128x64 (split over quadrants).
// BK=64 K-tiles; LDS = [A,B][slotset][half] half-tile slots (8 x 16KB = 128KB).
// Per phase: ds-load frag subtile, stage 1 half-tile (2 x global_load_lds), barrier,
// 16 MFMA (setprio), barrier. vmcnt(6) ONLY at phases 0 and 4 (3 half-tiles in flight).
// LDS swizzle: chunk16 ^= (row&7), applied via inverse-swizzled global source (involution).

template <bool OUT_BF16>
__global__ __launch_bounds__(512, 2) void k_gemm256(const unsigned short* __restrict__ A,
                                                    const unsigned short* __restrict__ Bt,
                                                    const float* __restrict__ bias,
                                                    void* __restrict__ Cout) {
    __shared__ __align__(16) unsigned short lds[2][2][2][8192];  // [mat][set][half][128*64]
    const int tid = threadIdx.x;
    const int w = tid >> 6, lane = tid & 63;
    const int wm = w >> 2, wn = w & 3;

    // XCD-bijective swizzle: 256 blocks = 64(M) x 4(N)
    const int bid = blockIdx.x;
    const int swz = (bid & 7) * 32 + (bid >> 3);
    const int m0 = (swz >> 2) * 256;
    const int n0 = (swz & 3) * 256;

    // staging geometry: thread t covers (row = w*8 + lane/8 [+64], chunk = lane&7) of a half-tile;
    // source chunk = chunk ^ (row&7)  (row&7 == lane>>3 for inst1 and inst2)
    const int sr = (w << 3) + (lane >> 3);
    const int sc = (lane & 7) ^ ((lane >> 3) & 7);
    const size_t aoff1 = (size_t)(m0 + sr) * 1024 + (size_t)(sc * 8);
    const size_t boff1 = (size_t)(n0 + sr) * 1024 + (size_t)(sc * 8);

    // frag read geometry (read back with chunk ^= row&7; row&7 == fr&7)
    const int fr = lane & 15, kq = lane >> 4;
    const int cs0 = ((kq) ^ (fr & 7)) * 8;
    const int cs1 = ((4 + kq) ^ (fr & 7)) * 8;
    const int arow = (wm * 64 + fr) * 64;
    const int brow = (wn * 32 + fr) * 64;

    f32x4 acc[2][2][4][2];
    const f32x4 zero = {0.f, 0.f, 0.f, 0.f};
#pragma unroll
    for (int qm = 0; qm < 2; ++qm)
#pragma unroll
        for (int qn = 0; qn < 2; ++qn)
#pragma unroll
            for (int i = 0; i < 4; ++i)
#pragma unroll
                for (int j = 0; j < 2; ++j) acc[qm][qn][i][j] = zero;

    bf16x8 af[4][2], bl[2][2], bh[2][2];

#define STAGE(mat, set, half, kt) do {                                                  \
        const unsigned short* g_ = ((mat) ? Bt : A) + ((mat) ? boff1 : aoff1)           \
                                   + (size_t)(half) * 131072 + (size_t)(kt);            \
        unsigned short* d_ = &lds[mat][set][half][0] + w * 512;                         \
        gload_lds16(g_, d_);                                                            \
        gload_lds16(g_ + 65536, d_ + 4096);                                             \
    } while (0)

#define LDA(set, qm) do {                                                               \
        const unsigned short* s_ = &lds[0][set][qm][0];                                 \
        _Pragma("unroll") for (int i = 0; i < 4; ++i) {                                 \
            af[i][0] = *(const bf16x8*)(s_ + arow + i * 1024 + cs0);                    \
            af[i][1] = *(const bf16x8*)(s_ + arow + i * 1024 + cs1);                    \
        }                                                                               \
    } while (0)

#define LDB(dst, set, qn) do {                                                          \
        const unsigned short* s_ = &lds[1][set][qn][0];                                 \
        _Pragma("unroll") for (int j = 0; j < 2; ++j) {                                 \
            dst[j][0] = *(const bf16x8*)(s_ + brow + j * 1024 + cs0);                   \
            dst[j][1] = *(const bf16x8*)(s_ + brow + j * 1024 + cs1);                   \
        }                                                                               \
    } while (0)

#define MM(qm, qn, B_) do {                                                             \
        __builtin_amdgcn_s_setprio(1);                                                  \
        _Pragma("unroll") for (int i = 0; i < 4; ++i)                                   \
        _Pragma("unroll") for (int j = 0; j < 2; ++j)                                   \
        _Pragma("unroll") for (int kk = 0; kk < 2; ++kk)                                \
            acc[qm][qn][i][j] = __builtin_amdgcn_mfma_f32_16x16x32_bf16(                \
                af[i][kk], B_[j][kk], acc[qm][qn][i][j], 0, 0, 0);                      \
        __builtin_amdgcn_s_setprio(0);                                                  \
    } while (0)

#define BAR() do { __builtin_amdgcn_s_barrier(); asm volatile("" ::: "memory"); } while (0)

    // prologue: tile0 -> set0 {B0,A0,B1,A1}; tile1 -> set1 {A0,B1,A1}  (7 half-tiles, 14 loads)
    STAGE(1, 0, 0, 0);
    STAGE(0, 0, 0, 0);
    STAGE(1, 0, 1, 0);
    STAGE(0, 0, 1, 0);
    STAGE(0, 1, 0, 64);
    STAGE(1, 1, 1, 64);
    STAGE(0, 1, 1, 64);

#pragma unroll 1
    for (int it = 0; it < 8; ++it) {
        const int kt = it * 128;
        // ---- K-tile even (slotset0): phases (0,0) (0,1) (1,1) (1,0) ----
        // p0
        STAGE(1, 1, 0, kt + 64);          // tile(2i+1).B0 -> B0s1
        wait_vmcnt<6>();
        BAR();
        LDA(0, 0); LDB(bl, 0, 0);
        MM(0, 0, bl);
        BAR();
        // p1
        LDB(bh, 0, 1);
        STAGE(1, 0, 0, kt + 128);         // tile(2i+2).B0 -> B0s0
        BAR();
        MM(0, 1, bh);
        BAR();
        // p2
        LDA(0, 1);
        STAGE(0, 0, 0, kt + 128);         // tile(2i+2).A0 -> A0s0
        BAR();
        MM(1, 1, bh);
        BAR();
        // p3
        STAGE(1, 0, 1, kt + 128);         // tile(2i+2).B1 -> B1s0
        BAR();
        MM(1, 0, bl);
        BAR();
        // ---- K-tile odd (slotset1) ----
        // p4
        STAGE(0, 0, 1, kt + 128);         // tile(2i+2).A1 -> A1s0
        wait_vmcnt<6>();
        BAR();
        LDA(1, 0); LDB(bl, 1, 0);
        MM(0, 0, bl);
        BAR();
        // p5
        LDB(bh, 1, 1);
        STAGE(0, 1, 0, kt + 192);         // tile(2i+3).A0 -> A0s1
        BAR();
        MM(0, 1, bh);
        BAR();
        // p6
        LDA(1, 1);
        STAGE(1, 1, 1, kt + 192);         // tile(2i+3).B1 -> B1s1
        BAR();
        MM(1, 1, bh);
        BAR();
        // p7
        STAGE(0, 1, 1, kt + 192);         // tile(2i+3).A1 -> A1s1
        BAR();
        MM(1, 0, bl);
        BAR();
    }
    wait_vmcnt<0>();   // drain tail junk stages

#undef STAGE
#undef LDA
#undef LDB
#undef MM
#undef BAR

#pragma unroll
    for (int qm = 0; qm < 2; ++qm) {
#pragma unroll
        for (int qn = 0; qn < 2; ++qn) {
#pragma unroll
            for (int i = 0; i < 4; ++i) {
#pragma unroll
                for (int j = 0; j < 2; ++j) {
                    const int col = n0 + qn * 128 + wn * 32 + j * 16 + fr;
                    const float bcol = bias[col];
#pragma unroll
                    for (int r = 0; r < 4; ++r) {
                        const int row = m0 + qm * 128 + wm * 64 + i * 16 + kq * 4 + r;
                        const float v = acc[qm][qn][i][j][r] + bcol;
                        if (OUT_BF16)
                            ((unsigned short*)Cout)[(size_t)row * D_MODEL + col] = f2bf(v);
                        else
                            ((float*)Cout)[(size_t)row * D_MODEL + col] = v;
                    }
                }
            }
        }
    }
}

// ---------------- off/attn projection: C96(M,96) = q @ [Woff|Wattn] + bias ----------------
// fp32-accurate via bf16 hi/lo: q_hi*w_hi + q_hi*w_lo + q_lo*w_hi.

__global__ void k_offattn(const unsigned short* __restrict__ qhi,
                          const unsigned short* __restrict__ qlo,
                          const unsigned short* __restrict__ WcTh,
                          const unsigned short* __restrict__ WcTl,
                          const float* __restrict__ boff,
                          const float* __restrict__ battn,
                          float* __restrict__ C96) {
    __shared__ unsigned short As[64 * 64];
    __shared__ unsigned short Bs[96 * 64];
    const int tid = threadIdx.x;
    const int w = tid >> 6, lane = tid & 63;
    const int wr = w >> 1, wc = w & 1;
    const int m0 = blockIdx.x * 64;

    f32x4 acc[2][3];
    const f32x4 zero = {0.f, 0.f, 0.f, 0.f};
#pragma unroll
    for (int i = 0; i < 2; ++i)
#pragma unroll
        for (int j = 0; j < 3; ++j) acc[i][j] = zero;

    const int ldrow = lane >> 3;
    const int ke = (lane & 7) * 8;

    for (int term = 0; term < 3; ++term) {
        const unsigned short* Ag = (term == 2) ? qlo : qhi;
        const unsigned short* Bg = (term == 1) ? WcTl : WcTh;
        for (int kt = 0; kt < D_MODEL; kt += 64) {
            __syncthreads();
#pragma unroll
            for (int j = 0; j < 2; ++j) {
                const int ra = w * 16 + j * 8 + ldrow;
                gload_lds16(Ag + (size_t)(m0 + ra) * D_MODEL + kt + ke, As + (w * 16 + j * 8) * 64);
            }
            if (w < 3) {
#pragma unroll
                for (int j = 0; j < 4; ++j) {
                    const int rb = w * 32 + j * 8 + ldrow;
                    gload_lds16(Bg + (size_t)rb * D_MODEL + kt + ke, Bs + (w * 32 + j * 8) * 64);
                }
            }
            __syncthreads();
#pragma unroll
            for (int kk = 0; kk < 2; ++kk) {
                const int ko = kk * 32 + (lane >> 4) * 8;
                bf16x8 af[2], bfr[3];
#pragma unroll
                for (int i = 0; i < 2; ++i)
                    af[i] = *(const bf16x8*)(As + (wr * 32 + i * 16 + (lane & 15)) * 64 + ko);
#pragma unroll
                for (int j = 0; j < 3; ++j)
                    bfr[j] = *(const bf16x8*)(Bs + (wc * 48 + j * 16 + (lane & 15)) * 64 + ko);
#pragma unroll
                for (int i = 0; i < 2; ++i)
#pragma unroll
                    for (int j = 0; j < 3; ++j)
                        acc[i][j] = __builtin_amdgcn_mfma_f32_16x16x32_bf16(af[i], bfr[j], acc[i][j], 0, 0, 0);
            }
        }
    }

#pragma unroll
    for (int i = 0; i < 2; ++i) {
#pragma unroll
        for (int j = 0; j < 3; ++j) {
            const int col = wc * 48 + j * 16 + (lane & 15);
            const float bcol = (col < 64) ? boff[col] : battn[col - 64];
#pragma unroll
            for (int r = 0; r < 4; ++r) {
                const int row = m0 + wr * 32 + i * 16 + (lane >> 4) * 4 + r;
                C96[(size_t)row * 96 + col] = acc[i][j][r] + bcol;
            }
        }
    }
}

// ---------------- sampler: softmax + bilinear gather + weighted sum ----------------

__global__ void k_sampler(const float* __restrict__ C96,
                          const unsigned short* __restrict__ vproj,
                          unsigned short* __restrict__ agg) {
    const int row = blockIdx.x;          // b*L + l
    const int b = row >> 12;
    const int l = row & (L_Q - 1);
    const int t = threadIdx.x;

    __shared__ float cv[96];
    if (t < 96) cv[t] = C96[(size_t)row * 96 + t];
    __syncthreads();

    const int h = t >> 5;
    const int dd = (t & 31) * 4;
    const float ref_y = (float)l / 4095.0f;

    float lg[4];
#pragma unroll
    for (int p = 0; p < 4; ++p) lg[p] = cv[64 + h * 4 + p];
    const float mx = fmaxf(fmaxf(lg[0], lg[1]), fmaxf(lg[2], lg[3]));
    float ex[4];
    float es = 0.f;
#pragma unroll
    for (int p = 0; p < 4; ++p) { ex[p] = expf(lg[p] - mx); es += ex[p]; }
    const float inv = 1.0f / es;

    float acc0 = 0.f, acc1 = 0.f, acc2 = 0.f, acc3 = 0.f;
#pragma unroll
    for (int p = 0; p < 4; ++p) {
        const float ox = cv[h * 8 + p * 2];
        const float oy = cv[h * 8 + p * 2 + 1];
        const float lx = fminf(fmaxf(ox, 0.0f), 1.0f);               // ref_x = 0
        const float ly = fminf(fmaxf(ref_y + oy, 0.0f), 1.0f);
        const float ux = (lx + 1.0f) * 2048.0f - 0.5f;               // ((x+1)*L - 1)/2
        const float wy = 1.0f - ly * 0.5f;                           // uy in [0,0.5] -> wy = 1-uy
        const float x0f = floorf(ux);
        const int i0 = (int)x0f;
        const int i1 = i0 + 1;
        const float w1 = ux - x0f;
        const float w0 = 1.0f - w1;
        const float aw = ex[p] * inv * wy;
        const float f0 = aw * w0 * ((i0 >= 0 && i0 < L_Q) ? 1.0f : 0.0f);
        const float f1 = aw * w1 * ((i1 >= 0 && i1 < L_Q) ? 1.0f : 0.0f);
        const int i0c = i0 < 0 ? 0 : (i0 > L_Q - 1 ? L_Q - 1 : i0);
        const int i1c = i1 < 0 ? 0 : (i1 > L_Q - 1 ? L_Q - 1 : i1);
        const ushort4 v0 = *(const ushort4*)(vproj + (size_t)(b * L_Q + i0c) * D_MODEL + h * 128 + dd);
        const ushort4 v1 = *(const ushort4*)(vproj + (size_t)(b * L_Q + i1c) * D_MODEL + h * 128 + dd);
        acc0 += f0 * bf2f(v0.x) + f1 * bf2f(v1.x);
        acc1 += f0 * bf2f(v0.y) + f1 * bf2f(v1.y);
        acc2 += f0 * bf2f(v0.z) + f1 * bf2f(v1.z);
        acc3 += f0 * bf2f(v0.w) + f1 * bf2f(v1.w);
    }
    ushort4 o;
    o.x = f2bf(acc0); o.y = f2bf(acc1); o.z = f2bf(acc2); o.w = f2bf(acc3);
    *(ushort4*)(agg + (size_t)row * D_MODEL + t * 4) = o;
}

// ---------------- launch ----------------

extern "C" void kernel_launch(void* const* d_in, const int* in_sizes, int n_in,
                              void* d_out, int out_size, void* d_ws, size_t ws_size,
                              hipStream_t stream) {
    const float* query = (const float*)d_in[0];
    // d_in[1] key_in: unused (dead code in reference)
    const float* value = (const float*)d_in[2];
    // d_in[3] Wqk, d_in[4] bqk: unused (dead code)
    const float* Wv    = (const float*)d_in[5];
    const float* bv    = (const float*)d_in[6];
    const float* Woff  = (const float*)d_in[7];
    const float* boff  = (const float*)d_in[8];
    const float* Wattn = (const float*)d_in[9];
    const float* battn = (const float*)d_in[10];
    const float* Wo    = (const float*)d_in[11];
    const float* bo    = (const float*)d_in[12];

    char* ws = (char*)d_ws;
    size_t off = 0;
    auto alloc = [&](size_t bytes) -> char* {
        char* p = ws + off;
        off += (bytes + 255) & ~(size_t)255;
        return p;
    };
    unsigned short* val_bf = (unsigned short*)alloc((size_t)M_ROWS * D_MODEL * 2);  // 32MB
    unsigned short* qhi    = (unsigned short*)alloc((size_t)M_ROWS * D_MODEL * 2);  // 32MB
    unsigned short* qlo    = (unsigned short*)alloc((size_t)M_ROWS * D_MODEL * 2);  // 32MB
    unsigned short* vproj  = (unsigned short*)alloc((size_t)M_ROWS * D_MODEL * 2);  // 32MB
    unsigned short* agg    = (unsigned short*)alloc((size_t)M_ROWS * D_MODEL * 2);  // 32MB
    float*          C96    = (float*)alloc((size_t)M_ROWS * 96 * 4);                // 6MB
    unsigned short* WvT    = (unsigned short*)alloc((size_t)D_MODEL * D_MODEL * 2); // 2MB
    unsigned short* WoT    = (unsigned short*)alloc((size_t)D_MODEL * D_MODEL * 2); // 2MB
    unsigned short* WcTh   = (unsigned short*)alloc((size_t)96 * D_MODEL * 2);
    unsigned short* WcTl   = (unsigned short*)alloc((size_t)96 * D_MODEL * 2);

    const int n4 = M_ROWS * D_MODEL / 4;
    k_cast_value<<<2048, 256, 0, stream>>>(value, val_bf, n4);
    k_split_query<<<2048, 256, 0, stream>>>(query, qhi, qlo, n4);
    k_prep_weights<<<1024, 256, 0, stream>>>(Wv, Wo, Woff, Wattn, WvT, WoT, WcTh, WcTl);

    // v = value @ Wv + bv   (bf16 out)
    k_gemm256<true><<<256, 512, 0, stream>>>(val_bf, WvT, bv, vproj);

    // C96 = query @ [Woff|Wattn] + [boff|battn]   (fp32-accurate hi/lo)
    k_offattn<<<M_ROWS / 64, 256, 0, stream>>>(qhi, qlo, WcTh, WcTl, boff, battn, C96);

    // agg = deformable sample + attn-weighted sum  (bf16 out)
    k_sampler<<<M_ROWS, 256, 0, stream>>>(C96, vproj, agg);

    // out = agg @ Wo + bo   (f32 out)
    k_gemm256<false><<<256, 512, 0, stream>>>(agg, WoT, bo, (float*)d_out);
}

// Round 5
// 191.970 us; speedup vs baseline: 1.1324x; 1.0356x over previous
//
#include <hip/hip_runtime.h>

#define L_Q 4096
#define D_MODEL 1024
#define N_B 4
#define N_H 8
#define N_P 4
#define M_ROWS (N_B * L_Q)   // 16384

typedef float f32x4 __attribute__((ext_vector_type(4)));
typedef __bf16 bf16x8 __attribute__((ext_vector_type(8)));

__device__ __forceinline__ unsigned short f2bf(float f) {
    unsigned int u = __float_as_uint(f);
    u += 0x7FFFu + ((u >> 16) & 1u);      // round-to-nearest-even
    return (unsigned short)(u >> 16);
}
__device__ __forceinline__ float bf2f(unsigned short s) {
    return __uint_as_float(((unsigned int)s) << 16);
}

// async global->LDS, 16B per lane; LDS dest = wave-uniform base + lane*16
__device__ __forceinline__ void gload_lds16(const void* g, void* l) {
    __builtin_amdgcn_global_load_lds((const __attribute__((address_space(1))) void*)g,
                                     (__attribute__((address_space(3))) void*)l,
                                     16, 0, 0);
}

template <int N> __device__ __forceinline__ void wait_vmc() {
    if constexpr (N == 9)      asm volatile("s_waitcnt vmcnt(9)"  ::: "memory");
    else if constexpr (N == 6) asm volatile("s_waitcnt vmcnt(6)"  ::: "memory");
    else if constexpr (N == 4) asm volatile("s_waitcnt vmcnt(4)"  ::: "memory");
    else if constexpr (N == 3) asm volatile("s_waitcnt vmcnt(3)"  ::: "memory");
    else if constexpr (N == 2) asm volatile("s_waitcnt vmcnt(2)"  ::: "memory");
    else                       asm volatile("s_waitcnt vmcnt(0)"  ::: "memory");
}

// ---------------- prep kernels ----------------

__global__ void k_cast_value(const float* __restrict__ in, unsigned short* __restrict__ out, int n4) {
    int i = blockIdx.x * blockDim.x + threadIdx.x;
    const int stride = gridDim.x * blockDim.x;
    for (; i < n4; i += stride) {
        float4 v = ((const float4*)in)[i];
        ushort4 o;
        o.x = f2bf(v.x); o.y = f2bf(v.y); o.z = f2bf(v.z); o.w = f2bf(v.w);
        ((ushort4*)out)[i] = o;
    }
}

__global__ void k_split_query(const float* __restrict__ q, unsigned short* __restrict__ hi,
                              unsigned short* __restrict__ lo, int n4) {
    int i = blockIdx.x * blockDim.x + threadIdx.x;
    const int stride = gridDim.x * blockDim.x;
    for (; i < n4; i += stride) {
        float4 v = ((const float4*)q)[i];
        ushort4 h, l;
        h.x = f2bf(v.x); l.x = f2bf(v.x - bf2f(h.x));
        h.y = f2bf(v.y); l.y = f2bf(v.y - bf2f(h.y));
        h.z = f2bf(v.z); l.z = f2bf(v.z - bf2f(h.z));
        h.w = f2bf(v.w); l.w = f2bf(v.w - bf2f(h.w));
        ((ushort4*)hi)[i] = h;
        ((ushort4*)lo)[i] = l;
    }
}

// WvT/WoT: (N=1024,K=1024) bf16 transposes.
// WcT3: (96, 3072) rows n = [Wh[n](k=0..1023) | Wl[n] | Wh[n]] for the 3-term hi/lo GEMM.
__global__ void k_prep_weights(const float* __restrict__ Wv, const float* __restrict__ Wo,
                               const float* __restrict__ Woff, const float* __restrict__ Wattn,
                               unsigned short* __restrict__ WvT, unsigned short* __restrict__ WoT,
                               unsigned short* __restrict__ WcT3) {
    const int n1 = D_MODEL * D_MODEL;
    const int n2 = 2 * n1;
    const int n3 = n2 + 96 * 3072;
    int i = blockIdx.x * blockDim.x + threadIdx.x;
    const int stride = gridDim.x * blockDim.x;
    for (; i < n3; i += stride) {
        if (i < n1) {
            int n = i >> 10, k = i & 1023;
            WvT[i] = f2bf(Wv[k * D_MODEL + n]);
        } else if (i < n2) {
            int j = i - n1;
            int n = j >> 10, k = j & 1023;
            WoT[j] = f2bf(Wo[k * D_MODEL + n]);
        } else {
            int j = i - n2;                 // j = row*3072 + seg*1024 + k
            int u = j >> 10;                // row*3 + seg
            int k = j & 1023;
            int row = u / 3;
            int seg = u - row * 3;
            float w = (row < 64) ? Woff[k * 64 + row] : Wattn[k * 32 + (row - 64)];
            unsigned short h = f2bf(w);
            WcT3[j] = (seg == 1) ? f2bf(w - bf2f(h)) : h;
        }
    }
}

// ---------------- 256x256 8-phase bf16 MFMA GEMM (m201 template): C = A(M,K)*Bt(N,K)^T + bias ----

template <bool OUT_BF16>
__global__ __launch_bounds__(512, 2) void k_gemm256(const unsigned short* __restrict__ A,
                                                    const unsigned short* __restrict__ Bt,
                                                    const float* __restrict__ bias,
                                                    void* __restrict__ Cout) {
    __shared__ __align__(16) unsigned short lds[2][2][2][8192];  // [mat][set][half][128*64]
    const int tid = threadIdx.x;
    const int w = tid >> 6, lane = tid & 63;
    const int wm = w >> 2, wn = w & 3;

    // XCD-bijective swizzle: 256 blocks = 64(M) x 4(N)
    const int bid = blockIdx.x;
    const int swz = (bid & 7) * 32 + (bid >> 3);
    const int m0 = (swz >> 2) * 256;
    const int n0 = (swz & 3) * 256;

    const int sr = (w << 3) + (lane >> 3);
    const int sc = (lane & 7) ^ ((lane >> 3) & 7);
    const size_t aoff1 = (size_t)(m0 + sr) * 1024 + (size_t)(sc * 8);
    const size_t boff1 = (size_t)(n0 + sr) * 1024 + (size_t)(sc * 8);

    const int fr = lane & 15, kq = lane >> 4;
    const int cs0 = ((kq) ^ (fr & 7)) * 8;
    const int cs1 = ((4 + kq) ^ (fr & 7)) * 8;
    const int arow = (wm * 64 + fr) * 64;
    const int brow = (wn * 32 + fr) * 64;

    f32x4 acc[2][2][4][2];
    const f32x4 zero = {0.f, 0.f, 0.f, 0.f};
#pragma unroll
    for (int qm = 0; qm < 2; ++qm)
#pragma unroll
        for (int qn = 0; qn < 2; ++qn)
#pragma unroll
            for (int i = 0; i < 4; ++i)
#pragma unroll
                for (int j = 0; j < 2; ++j) acc[qm][qn][i][j] = zero;

    bf16x8 af[4][2], bl[2][2], bh[2][2];

#define STAGE(mat, set, half, kt) do {                                                  \
        const unsigned short* g_ = ((mat) ? Bt : A) + ((mat) ? boff1 : aoff1)           \
                                   + (size_t)(half) * 131072 + (size_t)(kt);            \
        unsigned short* d_ = &lds[mat][set][half][0] + w * 512;                         \
        gload_lds16(g_, d_);                                                            \
        gload_lds16(g_ + 65536, d_ + 4096);                                             \
    } while (0)

#define LDA(set, qm) do {                                                               \
        const unsigned short* s_ = &lds[0][set][qm][0];                                 \
        _Pragma("unroll") for (int i = 0; i < 4; ++i) {                                 \
            af[i][0] = *(const bf16x8*)(s_ + arow + i * 1024 + cs0);                    \
            af[i][1] = *(const bf16x8*)(s_ + arow + i * 1024 + cs1);                    \
        }                                                                               \
    } while (0)

#define LDB(dst, set, qn) do {                                                          \
        const unsigned short* s_ = &lds[1][set][qn][0];                                 \
        _Pragma("unroll") for (int j = 0; j < 2; ++j) {                                 \
            dst[j][0] = *(const bf16x8*)(s_ + brow + j * 1024 + cs0);                   \
            dst[j][1] = *(const bf16x8*)(s_ + brow + j * 1024 + cs1);                   \
        }                                                                               \
    } while (0)

#define MM(qm, qn, B_) do {                                                             \
        __builtin_amdgcn_s_setprio(1);                                                  \
        _Pragma("unroll") for (int i = 0; i < 4; ++i)                                   \
        _Pragma("unroll") for (int j = 0; j < 2; ++j)                                   \
        _Pragma("unroll") for (int kk = 0; kk < 2; ++kk)                                \
            acc[qm][qn][i][j] = __builtin_amdgcn_mfma_f32_16x16x32_bf16(                \
                af[i][kk], B_[j][kk], acc[qm][qn][i][j], 0, 0, 0);                      \
        __builtin_amdgcn_s_setprio(0);                                                  \
    } while (0)

#define BAR() do { __builtin_amdgcn_s_barrier(); asm volatile("" ::: "memory"); } while (0)

    // prologue: tile0 -> set0 {B0,A0,B1,A1}; tile1 -> set1 {A0,B1,A1}
    STAGE(1, 0, 0, 0);
    STAGE(0, 0, 0, 0);
    STAGE(1, 0, 1, 0);
    STAGE(0, 0, 1, 0);
    STAGE(0, 1, 0, 64);
    STAGE(1, 1, 1, 64);
    STAGE(0, 1, 1, 64);

#pragma unroll 1
    for (int it = 0; it < 8; ++it) {
        const int kt = it * 128;
        // p0
        STAGE(1, 1, 0, kt + 64);
        wait_vmc<6>();
        BAR();
        LDA(0, 0); LDB(bl, 0, 0);
        MM(0, 0, bl);
        BAR();
        // p1
        LDB(bh, 0, 1);
        STAGE(1, 0, 0, kt + 128);
        BAR();
        MM(0, 1, bh);
        BAR();
        // p2
        LDA(0, 1);
        STAGE(0, 0, 0, kt + 128);
        BAR();
        MM(1, 1, bh);
        BAR();
        // p3
        STAGE(1, 0, 1, kt + 128);
        BAR();
        MM(1, 0, bl);
        BAR();
        // p4
        STAGE(0, 0, 1, kt + 128);
        wait_vmc<6>();
        BAR();
        LDA(1, 0); LDB(bl, 1, 0);
        MM(0, 0, bl);
        BAR();
        // p5
        LDB(bh, 1, 1);
        STAGE(0, 1, 0, kt + 192);
        BAR();
        MM(0, 1, bh);
        BAR();
        // p6
        LDA(1, 1);
        STAGE(1, 1, 1, kt + 192);
        BAR();
        MM(1, 1, bh);
        BAR();
        // p7
        STAGE(0, 1, 1, kt + 192);
        BAR();
        MM(1, 0, bl);
        BAR();
    }
    wait_vmc<0>();   // drain tail junk stages

#undef STAGE
#undef LDA
#undef LDB
#undef MM
#undef BAR

#pragma unroll
    for (int qm = 0; qm < 2; ++qm) {
#pragma unroll
        for (int qn = 0; qn < 2; ++qn) {
#pragma unroll
            for (int i = 0; i < 4; ++i) {
#pragma unroll
                for (int j = 0; j < 2; ++j) {
                    const int col = n0 + qn * 128 + wn * 32 + j * 16 + fr;
                    const float bcol = bias[col];
#pragma unroll
                    for (int r = 0; r < 4; ++r) {
                        const int row = m0 + qm * 128 + wm * 64 + i * 16 + kq * 4 + r;
                        const float v = acc[qm][qn][i][j][r] + bcol;
                        if (OUT_BF16)
                            ((unsigned short*)Cout)[(size_t)row * D_MODEL + col] = f2bf(v);
                        else
                            ((float*)Cout)[(size_t)row * D_MODEL + col] = v;
                    }
                }
            }
        }
    }
}

// ---------------- off/attn projection as pipelined K=3072 GEMM ----------------
// C96(M,96) = [qhi|qhi|qlo](M,3072) @ WcT3(96,3072)^T + bias  (== qhi*Wh + qhi*Wl + qlo*Wh)
// BM=64, 512 threads = 8 waves (4M x 2N of 48 cols). Ring of 4 LDS slices (80KB),
// counted vmcnt (never drained in loop), chunk^row&7 swizzle both sides.

__global__ __launch_bounds__(512, 2) void k_offattn2(const unsigned short* __restrict__ qhi,
                                                     const unsigned short* __restrict__ qlo,
                                                     const unsigned short* __restrict__ WcT3,
                                                     const float* __restrict__ boff,
                                                     const float* __restrict__ battn,
                                                     float* __restrict__ C96) {
    __shared__ __align__(16) unsigned short ldsA[4][4096];   // 64 rows x 64 k
    __shared__ __align__(16) unsigned short ldsB[4][6144];   // 96 rows x 64 k
    const int tid = threadIdx.x;
    const int w = tid >> 6, lane = tid & 63;
    const int wm = w >> 1, wn = w & 1;
    const int m0 = blockIdx.x * 64;
    const bool wlo = (w < 4);

    // staging geometry (chunk ^= row&7 on the global source; LDS stays linear)
    const int srow = lane >> 3;                       // 0..7 within 8-row group
    const int schk = (lane & 7) ^ (srow & 7);
    const size_t aoffs = (size_t)(m0 + w * 8 + srow) * 1024 + (size_t)(schk * 8);
    const int brow0 = wlo ? w * 16 : 64 + (w - 4) * 8;
    const size_t boffs0 = (size_t)(brow0 + srow) * 3072 + (size_t)(schk * 8);
    const size_t boffs1 = boffs0 + (size_t)8 * 3072;  // waves 0-3 second issue
    const int astg = w * 512;
    const int bstg0 = brow0 * 64;
    const int bstg1 = bstg0 + 512;

    // frag read geometry
    const int fr = lane & 15, kq = lane >> 4;
    const int cs0 = ((kq) ^ (fr & 7)) * 8;
    const int cs1 = ((4 + kq) ^ (fr & 7)) * 8;
    const int arow = (wm * 16 + fr) * 64;

    f32x4 acc[3];
    const f32x4 zero = {0.f, 0.f, 0.f, 0.f};
#pragma unroll
    for (int j = 0; j < 3; ++j) acc[j] = zero;

#define OSTAGE(s) do {                                                                  \
        const int slot_ = (s) & 3;                                                      \
        const size_t kc_ = ((s) < 32) ? (size_t)(((s) & 15) * 64)                       \
                                      : (size_t)(((s) - 32) * 64);                      \
        const unsigned short* ab_ = ((s) < 32) ? qhi : qlo;                             \
        gload_lds16(ab_ + aoffs + kc_, &ldsA[slot_][astg]);                             \
        gload_lds16(WcT3 + boffs0 + (size_t)(s) * 64, &ldsB[slot_][bstg0]);             \
        if (wlo) gload_lds16(WcT3 + boffs1 + (size_t)(s) * 64, &ldsB[slot_][bstg1]);    \
    } while (0)

#define OCOMP(t) do {                                                                   \
        const unsigned short* As_ = &ldsA[(t) & 3][0];                                  \
        const unsigned short* Bs_ = &ldsB[(t) & 3][0];                                  \
        bf16x8 af0 = *(const bf16x8*)(As_ + arow + cs0);                                \
        bf16x8 af1 = *(const bf16x8*)(As_ + arow + cs1);                                \
        bf16x8 bfr[3][2];                                                               \
        _Pragma("unroll") for (int j = 0; j < 3; ++j) {                                 \
            const int br_ = (wn * 48 + j * 16 + fr) * 64;                               \
            bfr[j][0] = *(const bf16x8*)(Bs_ + br_ + cs0);                              \
            bfr[j][1] = *(const bf16x8*)(Bs_ + br_ + cs1);                              \
        }                                                                               \
        __builtin_amdgcn_s_setprio(1);                                                  \
        _Pragma("unroll") for (int j = 0; j < 3; ++j) {                                 \
            acc[j] = __builtin_amdgcn_mfma_f32_16x16x32_bf16(af0, bfr[j][0], acc[j], 0, 0, 0); \
            acc[j] = __builtin_amdgcn_mfma_f32_16x16x32_bf16(af1, bfr[j][1], acc[j], 0, 0, 0); \
        }                                                                               \
        __builtin_amdgcn_s_setprio(0);                                                  \
    } while (0)

#define OBAR() do { __builtin_amdgcn_s_barrier(); asm volatile("" ::: "memory"); } while (0)

    OSTAGE(0); OSTAGE(1); OSTAGE(2);

#pragma unroll 1
    for (int t = 0; t < 45; ++t) {
        OSTAGE(t + 3);
        if (wlo) wait_vmc<9>(); else wait_vmc<6>();
        OBAR();
        OCOMP(t);
        OBAR();
    }
    if (wlo) wait_vmc<6>(); else wait_vmc<4>();
    OBAR(); OCOMP(45); OBAR();
    if (wlo) wait_vmc<3>(); else wait_vmc<2>();
    OBAR(); OCOMP(46); OBAR();
    wait_vmc<0>();
    OBAR(); OCOMP(47); OBAR();

#undef OSTAGE
#undef OCOMP
#undef OBAR

#pragma unroll
    for (int j = 0; j < 3; ++j) {
        const int col = wn * 48 + j * 16 + fr;
        const float bcol = (col < 64) ? boff[col] : battn[col - 64];
#pragma unroll
        for (int r = 0; r < 4; ++r) {
            const int row = m0 + wm * 16 + kq * 4 + r;
            C96[(size_t)row * 96 + col] = acc[j][r] + bcol;
        }
    }
}

// ---------------- sampler: softmax + bilinear gather + weighted sum ----------------

__global__ void k_sampler(const float* __restrict__ C96,
                          const unsigned short* __restrict__ vproj,
                          unsigned short* __restrict__ agg) {
    const int row = blockIdx.x;          // b*L + l
    const int b = row >> 12;
    const int l = row & (L_Q - 1);
    const int t = threadIdx.x;

    __shared__ float cv[96];
    if (t < 96) cv[t] = C96[(size_t)row * 96 + t];
    __syncthreads();

    const int h = t >> 5;
    const int dd = (t & 31) * 4;
    const float ref_y = (float)l / 4095.0f;

    float lg[4];
#pragma unroll
    for (int p = 0; p < 4; ++p) lg[p] = cv[64 + h * 4 + p];
    const float mx = fmaxf(fmaxf(lg[0], lg[1]), fmaxf(lg[2], lg[3]));
    float ex[4];
    float es = 0.f;
#pragma unroll
    for (int p = 0; p < 4; ++p) { ex[p] = expf(lg[p] - mx); es += ex[p]; }
    const float inv = 1.0f / es;

    float acc0 = 0.f, acc1 = 0.f, acc2 = 0.f, acc3 = 0.f;
#pragma unroll
    for (int p = 0; p < 4; ++p) {
        const float ox = cv[h * 8 + p * 2];
        const float oy = cv[h * 8 + p * 2 + 1];
        const float lx = fminf(fmaxf(ox, 0.0f), 1.0f);               // ref_x = 0
        const float ly = fminf(fmaxf(ref_y + oy, 0.0f), 1.0f);
        const float ux = (lx + 1.0f) * 2048.0f - 0.5f;               // ((x+1)*L - 1)/2
        const float wy = 1.0f - ly * 0.5f;                           // uy in [0,0.5] -> wy = 1-uy
        const float x0f = floorf(ux);
        const int i0 = (int)x0f;
        const int i1 = i0 + 1;
        const float w1 = ux - x0f;
        const float w0 = 1.0f - w1;
        const float aw = ex[p] * inv * wy;
        const float f0 = aw * w0 * ((i0 >= 0 && i0 < L_Q) ? 1.0f : 0.0f);
        const float f1 = aw * w1 * ((i1 >= 0 && i1 < L_Q) ? 1.0f : 0.0f);
        const int i0c = i0 < 0 ? 0 : (i0 > L_Q - 1 ? L_Q - 1 : i0);
        const int i1c = i1 < 0 ? 0 : (i1 > L_Q - 1 ? L_Q - 1 : i1);
        const ushort4 v0 = *(const ushort4*)(vproj + (size_t)(b * L_Q + i0c) * D_MODEL + h * 128 + dd);
        const ushort4 v1 = *(const ushort4*)(vproj + (size_t)(b * L_Q + i1c) * D_MODEL + h * 128 + dd);
        acc0 += f0 * bf2f(v0.x) + f1 * bf2f(v1.x);
        acc1 += f0 * bf2f(v0.y) + f1 * bf2f(v1.y);
        acc2 += f0 * bf2f(v0.z) + f1 * bf2f(v1.z);
        acc3 += f0 * bf2f(v0.w) + f1 * bf2f(v1.w);
    }
    ushort4 o;
    o.x = f2bf(acc0); o.y = f2bf(acc1); o.z = f2bf(acc2); o.w = f2bf(acc3);
    *(ushort4*)(agg + (size_t)row * D_MODEL + t * 4) = o;
}

// ---------------- launch ----------------

extern "C" void kernel_launch(void* const* d_in, const int* in_sizes, int n_in,
                              void* d_out, int out_size, void* d_ws, size_t ws_size,
                              hipStream_t stream) {
    const float* query = (const float*)d_in[0];
    // d_in[1] key_in: unused (dead code in reference)
    const float* value = (const float*)d_in[2];
    // d_in[3] Wqk, d_in[4] bqk: unused (dead code)
    const float* Wv    = (const float*)d_in[5];
    const float* bv    = (const float*)d_in[6];
    const float* Woff  = (const float*)d_in[7];
    const float* boff  = (const float*)d_in[8];
    const float* Wattn = (const float*)d_in[9];
    const float* battn = (const float*)d_in[10];
    const float* Wo    = (const float*)d_in[11];
    const float* bo    = (const float*)d_in[12];

    char* ws = (char*)d_ws;
    size_t off = 0;
    auto alloc = [&](size_t bytes) -> char* {
        char* p = ws + off;
        off += (bytes + 255) & ~(size_t)255;
        return p;
    };
    unsigned short* val_bf = (unsigned short*)alloc((size_t)M_ROWS * D_MODEL * 2);  // 32MB
    unsigned short* qhi    = (unsigned short*)alloc((size_t)M_ROWS * D_MODEL * 2);  // 32MB
    unsigned short* qlo    = (unsigned short*)alloc((size_t)M_ROWS * D_MODEL * 2);  // 32MB
    unsigned short* vproj  = (unsigned short*)alloc((size_t)M_ROWS * D_MODEL * 2);  // 32MB
    unsigned short* agg    = (unsigned short*)alloc((size_t)M_ROWS * D_MODEL * 2);  // 32MB
    float*          C96    = (float*)alloc((size_t)M_ROWS * 96 * 4);                // 6MB
    unsigned short* WvT    = (unsigned short*)alloc((size_t)D_MODEL * D_MODEL * 2); // 2MB
    unsigned short* WoT    = (unsigned short*)alloc((size_t)D_MODEL * D_MODEL * 2); // 2MB
    unsigned short* WcT3   = (unsigned short*)alloc((size_t)96 * 3072 * 2);         // 0.6MB

    const int n4 = M_ROWS * D_MODEL / 4;
    k_cast_value<<<2048, 256, 0, stream>>>(value, val_bf, n4);
    k_split_query<<<2048, 256, 0, stream>>>(query, qhi, qlo, n4);
    k_prep_weights<<<1024, 256, 0, stream>>>(Wv, Wo, Woff, Wattn, WvT, WoT, WcT3);

    // v = value @ Wv + bv   (bf16 out)
    k_gemm256<true><<<256, 512, 0, stream>>>(val_bf, WvT, bv, vproj);

    // C96 = query @ [Woff|Wattn] + [boff|battn]   (fp32-accurate hi/lo, K=3072 concat GEMM)
    k_offattn2<<<M_ROWS / 64, 512, 0, stream>>>(qhi, qlo, WcT3, boff, battn, C96);

    // agg = deformable sample + attn-weighted sum  (bf16 out)
    k_sampler<<<M_ROWS, 256, 0, stream>>>(C96, vproj, agg);

    // out = agg @ Wo + bo   (f32 out)
    k_gemm256<false><<<256, 512, 0, stream>>>(agg, WoT, bo, (float*)d_out);
}

// Round 6
// 189.125 us; speedup vs baseline: 1.1494x; 1.0150x over previous
//
#include <hip/hip_runtime.h>

#define L_Q 4096
#define D_MODEL 1024
#define N_B 4
#define N_H 8
#define N_P 4
#define M_ROWS (N_B * L_Q)   // 16384

typedef float f32x4 __attribute__((ext_vector_type(4)));
typedef __bf16 bf16x8 __attribute__((ext_vector_type(8)));

__device__ __forceinline__ unsigned short f2bf(float f) {
    unsigned int u = __float_as_uint(f);
    u += 0x7FFFu + ((u >> 16) & 1u);      // round-to-nearest-even
    return (unsigned short)(u >> 16);
}
__device__ __forceinline__ float bf2f(unsigned short s) {
    return __uint_as_float(((unsigned int)s) << 16);
}

// async global->LDS, 16B per lane; LDS dest = wave-uniform base + lane*16
__device__ __forceinline__ void gload_lds16(const void* g, void* l) {
    __builtin_amdgcn_global_load_lds((const __attribute__((address_space(1))) void*)g,
                                     (__attribute__((address_space(3))) void*)l,
                                     16, 0, 0);
}

template <int N> __device__ __forceinline__ void wait_vmc() {
    if constexpr (N == 9)      asm volatile("s_waitcnt vmcnt(9)"  ::: "memory");
    else if constexpr (N == 6) asm volatile("s_waitcnt vmcnt(6)"  ::: "memory");
    else if constexpr (N == 4) asm volatile("s_waitcnt vmcnt(4)"  ::: "memory");
    else if constexpr (N == 3) asm volatile("s_waitcnt vmcnt(3)"  ::: "memory");
    else if constexpr (N == 2) asm volatile("s_waitcnt vmcnt(2)"  ::: "memory");
    else                       asm volatile("s_waitcnt vmcnt(0)"  ::: "memory");
}

// ---------------- prep kernels ----------------

__global__ void k_cast_value(const float* __restrict__ in, unsigned short* __restrict__ out, int n4) {
    int i = blockIdx.x * blockDim.x + threadIdx.x;
    const int stride = gridDim.x * blockDim.x;
    for (; i < n4; i += stride) {
        float4 v = ((const float4*)in)[i];
        ushort4 o;
        o.x = f2bf(v.x); o.y = f2bf(v.y); o.z = f2bf(v.z); o.w = f2bf(v.w);
        ((ushort4*)out)[i] = o;
    }
}

__global__ void k_split_query(const float* __restrict__ q, unsigned short* __restrict__ hi,
                              unsigned short* __restrict__ lo, int n4) {
    int i = blockIdx.x * blockDim.x + threadIdx.x;
    const int stride = gridDim.x * blockDim.x;
    for (; i < n4; i += stride) {
        float4 v = ((const float4*)q)[i];
        ushort4 h, l;
        h.x = f2bf(v.x); l.x = f2bf(v.x - bf2f(h.x));
        h.y = f2bf(v.y); l.y = f2bf(v.y - bf2f(h.y));
        h.z = f2bf(v.z); l.z = f2bf(v.z - bf2f(h.z));
        h.w = f2bf(v.w); l.w = f2bf(v.w - bf2f(h.w));
        ((ushort4*)hi)[i] = h;
        ((ushort4*)lo)[i] = l;
    }
}

// WvT/WoT: (N=1024,K=1024) bf16 transposes.
// WcT3: (96, 3072) rows n = [Wh[n](k=0..1023) | Wl[n] | Wh[n]] for the 3-term hi/lo GEMM.
__global__ void k_prep_weights(const float* __restrict__ Wv, const float* __restrict__ Wo,
                               const float* __restrict__ Woff, const float* __restrict__ Wattn,
                               unsigned short* __restrict__ WvT, unsigned short* __restrict__ WoT,
                               unsigned short* __restrict__ WcT3) {
    const int n1 = D_MODEL * D_MODEL;
    const int n2 = 2 * n1;
    const int n3 = n2 + 96 * 3072;
    int i = blockIdx.x * blockDim.x + threadIdx.x;
    const int stride = gridDim.x * blockDim.x;
    for (; i < n3; i += stride) {
        if (i < n1) {
            int n = i >> 10, k = i & 1023;
            WvT[i] = f2bf(Wv[k * D_MODEL + n]);
        } else if (i < n2) {
            int j = i - n1;
            int n = j >> 10, k = j & 1023;
            WoT[j] = f2bf(Wo[k * D_MODEL + n]);
        } else {
            int j = i - n2;                 // j = row*3072 + seg*1024 + k
            int u = j >> 10;                // row*3 + seg
            int k = j & 1023;
            int row = u / 3;
            int seg = u - row * 3;
            float w = (row < 64) ? Woff[k * 64 + row] : Wattn[k * 32 + (row - 64)];
            unsigned short h = f2bf(w);
            WcT3[j] = (seg == 1) ? f2bf(w - bf2f(h)) : h;
        }
    }
}

// ---------------- 256x256 single-barrier 8-phase bf16 MFMA GEMM ----------------
// C = A(M,K)*Bt(N,K)^T + bias.  M=16384, N=K=1024. 512 threads = 8 waves (2M x 4N).
// Per phase: STAGE 1 half-tile -> counted vmcnt -> ONE barrier -> {ds_reads || 16 MFMA}.
// Read groups balanced 8,4,8,4,... via bl-prefetch at the 0-read phases (q3/q7).
// Phases 0-3 stage this iter's set1 (kt+64); phases 4-7 stage next iter's set0 (kt+128).
// LDS swizzle: chunk16 ^= (row&7), via inverse-swizzled global source (involution).

template <bool OUT_BF16>
__global__ __launch_bounds__(512, 2) void k_gemm256(const unsigned short* __restrict__ A,
                                                    const unsigned short* __restrict__ Bt,
                                                    const float* __restrict__ bias,
                                                    void* __restrict__ Cout) {
    __shared__ __align__(16) unsigned short lds[2][2][2][8192];  // [mat][set][half][128*64]
    const int tid = threadIdx.x;
    const int w = tid >> 6, lane = tid & 63;
    const int wm = w >> 2, wn = w & 3;

    // XCD-bijective swizzle: 256 blocks = 64(M) x 4(N)
    const int bid = blockIdx.x;
    const int swz = (bid & 7) * 32 + (bid >> 3);
    const int m0 = (swz >> 2) * 256;
    const int n0 = (swz & 3) * 256;

    const int sr = (w << 3) + (lane >> 3);
    const int sc = (lane & 7) ^ ((lane >> 3) & 7);
    const size_t aoff1 = (size_t)(m0 + sr) * 1024 + (size_t)(sc * 8);
    const size_t boff1 = (size_t)(n0 + sr) * 1024 + (size_t)(sc * 8);

    const int fr = lane & 15, kq = lane >> 4;
    const int cs0 = ((kq) ^ (fr & 7)) * 8;
    const int cs1 = ((4 + kq) ^ (fr & 7)) * 8;
    const int arow = (wm * 64 + fr) * 64;
    const int brow = (wn * 32 + fr) * 64;

    f32x4 acc[2][2][4][2];
    const f32x4 zero = {0.f, 0.f, 0.f, 0.f};
#pragma unroll
    for (int qm = 0; qm < 2; ++qm)
#pragma unroll
        for (int qn = 0; qn < 2; ++qn)
#pragma unroll
            for (int i = 0; i < 4; ++i)
#pragma unroll
                for (int j = 0; j < 2; ++j) acc[qm][qn][i][j] = zero;

    bf16x8 af[4][2], bl[2][2], bh[2][2];

#define STAGE(mat, set, half, kt) do {                                                  \
        const unsigned short* g_ = ((mat) ? Bt : A) + ((mat) ? boff1 : aoff1)           \
                                   + (size_t)(half) * 131072 + (size_t)(kt);            \
        unsigned short* d_ = &lds[mat][set][half][0] + w * 512;                         \
        gload_lds16(g_, d_);                                                            \
        gload_lds16(g_ + 65536, d_ + 4096);                                             \
    } while (0)

#define LDA(set, qm) do {                                                               \
        const unsigned short* s_ = &lds[0][set][qm][0];                                 \
        _Pragma("unroll") for (int i = 0; i < 4; ++i) {                                 \
            af[i][0] = *(const bf16x8*)(s_ + arow + i * 1024 + cs0);                    \
            af[i][1] = *(const bf16x8*)(s_ + arow + i * 1024 + cs1);                    \
        }                                                                               \
    } while (0)

#define LDB(dst, set, qn) do {                                                          \
        const unsigned short* s_ = &lds[1][set][qn][0];                                 \
        _Pragma("unroll") for (int j = 0; j < 2; ++j) {                                 \
            dst[j][0] = *(const bf16x8*)(s_ + brow + j * 1024 + cs0);                   \
            dst[j][1] = *(const bf16x8*)(s_ + brow + j * 1024 + cs1);                   \
        }                                                                               \
    } while (0)

#define MM(qm, qn, B_) do {                                                             \
        __builtin_amdgcn_s_setprio(1);                                                  \
        _Pragma("unroll") for (int i = 0; i < 4; ++i)                                   \
        _Pragma("unroll") for (int j = 0; j < 2; ++j)                                   \
        _Pragma("unroll") for (int kk = 0; kk < 2; ++kk)                                \
            acc[qm][qn][i][j] = __builtin_amdgcn_mfma_f32_16x16x32_bf16(                \
                af[i][kk], B_[j][kk], acc[qm][qn][i][j], 0, 0, 0);                      \
        __builtin_amdgcn_s_setprio(0);                                                  \
    } while (0)

#define BAR() do { __builtin_amdgcn_s_barrier(); asm volatile("" ::: "memory"); } while (0)

    // prologue: set0 @ kt=0 (4 half-tiles: A0,B0,B1,A1), then prefetch bl(B0s0)
    STAGE(0, 0, 0, 0);   // A0s0  loads <=2
    STAGE(1, 0, 0, 0);   // B0s0  loads <=4
    STAGE(1, 0, 1, 0);   // B1s0  loads <=6
    STAGE(0, 0, 1, 0);   // A1s0  loads <=8
    wait_vmc<4>();       // first 4 loads done (A0s0, B0s0)
    BAR();
    LDB(bl, 0, 0);

#pragma unroll 1
    for (int it = 0; it < 8; ++it) {
        const int kt = it * 128;
        // q0: stage A0s1; read af=A(set0,h0); MM quad(0,0)
        STAGE(0, 1, 0, kt + 64);
        wait_vmc<6>(); BAR();
        LDA(0, 0);
        MM(0, 0, bl);
        // q1: stage B0s1; read bh=B(set0,h1); MM quad(0,1)
        STAGE(1, 1, 0, kt + 64);
        wait_vmc<6>(); BAR();
        LDB(bh, 0, 1);
        MM(0, 1, bh);
        // q2: stage B1s1; read af=A(set0,h1); MM quad(1,1)
        STAGE(1, 1, 1, kt + 64);
        wait_vmc<6>(); BAR();
        LDA(0, 1);
        MM(1, 1, bh);
        // q3: stage A1s1; MM quad(1,0) (held regs); prefetch bl=B(set1,h0)
        STAGE(0, 1, 1, kt + 64);
        wait_vmc<4>(); BAR();
        MM(1, 0, bl);
        LDB(bl, 1, 0);
        // q4: stage next A0s0; read af=A(set1,h0); MM quad(0,0)
        STAGE(0, 0, 0, kt + 128);
        wait_vmc<6>(); BAR();
        LDA(1, 0);
        MM(0, 0, bl);
        // q5: stage next B0s0; read bh=B(set1,h1); MM quad(0,1)
        STAGE(1, 0, 0, kt + 128);
        wait_vmc<6>(); BAR();
        LDB(bh, 1, 1);
        MM(0, 1, bh);
        // q6: stage next B1s0; read af=A(set1,h1); MM quad(1,1)
        STAGE(1, 0, 1, kt + 128);
        wait_vmc<6>(); BAR();
        LDA(1, 1);
        MM(1, 1, bh);
        // q7: stage next A1s0; MM quad(1,0); prefetch bl=next B(set0,h0)
        STAGE(0, 0, 1, kt + 128);
        wait_vmc<4>(); BAR();
        MM(1, 0, bl);
        LDB(bl, 0, 0);
    }
    wait_vmc<0>();   // drain tail junk stages

#undef STAGE
#undef LDA
#undef LDB
#undef MM
#undef BAR

#pragma unroll
    for (int qm = 0; qm < 2; ++qm) {
#pragma unroll
        for (int qn = 0; qn < 2; ++qn) {
#pragma unroll
            for (int i = 0; i < 4; ++i) {
#pragma unroll
                for (int j = 0; j < 2; ++j) {
                    const int col = n0 + qn * 128 + wn * 32 + j * 16 + fr;
                    const float bcol = bias[col];
#pragma unroll
                    for (int r = 0; r < 4; ++r) {
                        const int row = m0 + qm * 128 + wm * 64 + i * 16 + kq * 4 + r;
                        const float v = acc[qm][qn][i][j][r] + bcol;
                        if (OUT_BF16)
                            ((unsigned short*)Cout)[(size_t)row * D_MODEL + col] = f2bf(v);
                        else
                            ((float*)Cout)[(size_t)row * D_MODEL + col] = v;
                    }
                }
            }
        }
    }
}

// ---------------- off/attn projection as pipelined K=3072 GEMM ----------------
// C96(M,96) = [qhi|qhi|qlo](M,3072) @ WcT3(96,3072)^T + bias  (== qhi*Wh + qhi*Wl + qlo*Wh)

__global__ __launch_bounds__(512, 2) void k_offattn2(const unsigned short* __restrict__ qhi,
                                                     const unsigned short* __restrict__ qlo,
                                                     const unsigned short* __restrict__ WcT3,
                                                     const float* __restrict__ boff,
                                                     const float* __restrict__ battn,
                                                     float* __restrict__ C96) {
    __shared__ __align__(16) unsigned short ldsA[4][4096];   // 64 rows x 64 k
    __shared__ __align__(16) unsigned short ldsB[4][6144];   // 96 rows x 64 k
    const int tid = threadIdx.x;
    const int w = tid >> 6, lane = tid & 63;
    const int wm = w >> 1, wn = w & 1;
    const int m0 = blockIdx.x * 64;
    const bool wlo = (w < 4);

    // staging geometry (chunk ^= row&7 on the global source; LDS stays linear)
    const int srow = lane >> 3;                       // 0..7 within 8-row group
    const int schk = (lane & 7) ^ (srow & 7);
    const size_t aoffs = (size_t)(m0 + w * 8 + srow) * 1024 + (size_t)(schk * 8);
    const int brow0 = wlo ? w * 16 : 64 + (w - 4) * 8;
    const size_t boffs0 = (size_t)(brow0 + srow) * 3072 + (size_t)(schk * 8);
    const size_t boffs1 = boffs0 + (size_t)8 * 3072;  // waves 0-3 second issue
    const int astg = w * 512;
    const int bstg0 = brow0 * 64;
    const int bstg1 = bstg0 + 512;

    // frag read geometry
    const int fr = lane & 15, kq = lane >> 4;
    const int cs0 = ((kq) ^ (fr & 7)) * 8;
    const int cs1 = ((4 + kq) ^ (fr & 7)) * 8;
    const int arow = (wm * 16 + fr) * 64;

    f32x4 acc[3];
    const f32x4 zero = {0.f, 0.f, 0.f, 0.f};
#pragma unroll
    for (int j = 0; j < 3; ++j) acc[j] = zero;

#define OSTAGE(s) do {                                                                  \
        const int slot_ = (s) & 3;                                                      \
        const size_t kc_ = ((s) < 32) ? (size_t)(((s) & 15) * 64)                       \
                                      : (size_t)(((s) - 32) * 64);                      \
        const unsigned short* ab_ = ((s) < 32) ? qhi : qlo;                             \
        gload_lds16(ab_ + aoffs + kc_, &ldsA[slot_][astg]);                             \
        gload_lds16(WcT3 + boffs0 + (size_t)(s) * 64, &ldsB[slot_][bstg0]);             \
        if (wlo) gload_lds16(WcT3 + boffs1 + (size_t)(s) * 64, &ldsB[slot_][bstg1]);    \
    } while (0)

#define OCOMP(t) do {                                                                   \
        const unsigned short* As_ = &ldsA[(t) & 3][0];                                  \
        const unsigned short* Bs_ = &ldsB[(t) & 3][0];                                  \
        bf16x8 af0 = *(const bf16x8*)(As_ + arow + cs0);                                \
        bf16x8 af1 = *(const bf16x8*)(As_ + arow + cs1);                                \
        bf16x8 bfr[3][2];                                                               \
        _Pragma("unroll") for (int j = 0; j < 3; ++j) {                                 \
            const int br_ = (wn * 48 + j * 16 + fr) * 64;                               \
            bfr[j][0] = *(const bf16x8*)(Bs_ + br_ + cs0);                              \
            bfr[j][1] = *(const bf16x8*)(Bs_ + br_ + cs1);                              \
        }                                                                               \
        __builtin_amdgcn_s_setprio(1);                                                  \
        _Pragma("unroll") for (int j = 0; j < 3; ++j) {                                 \
            acc[j] = __builtin_amdgcn_mfma_f32_16x16x32_bf16(af0, bfr[j][0], acc[j], 0, 0, 0); \
            acc[j] = __builtin_amdgcn_mfma_f32_16x16x32_bf16(af1, bfr[j][1], acc[j], 0, 0, 0); \
        }                                                                               \
        __builtin_amdgcn_s_setprio(0);                                                  \
    } while (0)

#define OBAR() do { __builtin_amdgcn_s_barrier(); asm volatile("" ::: "memory"); } while (0)

    OSTAGE(0); OSTAGE(1); OSTAGE(2);

#pragma unroll 1
    for (int t = 0; t < 45; ++t) {
        OSTAGE(t + 3);
        if (wlo) wait_vmc<9>(); else wait_vmc<6>();
        OBAR();
        OCOMP(t);
        OBAR();
    }
    if (wlo) wait_vmc<6>(); else wait_vmc<4>();
    OBAR(); OCOMP(45); OBAR();
    if (wlo) wait_vmc<3>(); else wait_vmc<2>();
    OBAR(); OCOMP(46); OBAR();
    wait_vmc<0>();
    OBAR(); OCOMP(47); OBAR();

#undef OSTAGE
#undef OCOMP
#undef OBAR

#pragma unroll
    for (int j = 0; j < 3; ++j) {
        const int col = wn * 48 + j * 16 + fr;
        const float bcol = (col < 64) ? boff[col] : battn[col - 64];
#pragma unroll
        for (int r = 0; r < 4; ++r) {
            const int row = m0 + wm * 16 + kq * 4 + r;
            C96[(size_t)row * 96 + col] = acc[j][r] + bcol;
        }
    }
}

// ---------------- sampler: softmax + bilinear gather + weighted sum ----------------

__global__ void k_sampler(const float* __restrict__ C96,
                          const unsigned short* __restrict__ vproj,
                          unsigned short* __restrict__ agg) {
    const int row = blockIdx.x;          // b*L + l
    const int b = row >> 12;
    const int l = row & (L_Q - 1);
    const int t = threadIdx.x;

    __shared__ float cv[96];
    if (t < 96) cv[t] = C96[(size_t)row * 96 + t];
    __syncthreads();

    const int h = t >> 5;
    const int dd = (t & 31) * 4;
    const float ref_y = (float)l / 4095.0f;

    float lg[4];
#pragma unroll
    for (int p = 0; p < 4; ++p) lg[p] = cv[64 + h * 4 + p];
    const float mx = fmaxf(fmaxf(lg[0], lg[1]), fmaxf(lg[2], lg[3]));
    float ex[4];
    float es = 0.f;
#pragma unroll
    for (int p = 0; p < 4; ++p) { ex[p] = expf(lg[p] - mx); es += ex[p]; }
    const float inv = 1.0f / es;

    float acc0 = 0.f, acc1 = 0.f, acc2 = 0.f, acc3 = 0.f;
#pragma unroll
    for (int p = 0; p < 4; ++p) {
        const float ox = cv[h * 8 + p * 2];
        const float oy = cv[h * 8 + p * 2 + 1];
        const float lx = fminf(fmaxf(ox, 0.0f), 1.0f);               // ref_x = 0
        const float ly = fminf(fmaxf(ref_y + oy, 0.0f), 1.0f);
        const float ux = (lx + 1.0f) * 2048.0f - 0.5f;               // ((x+1)*L - 1)/2
        const float wy = 1.0f - ly * 0.5f;                           // uy in [0,0.5] -> wy = 1-uy
        const float x0f = floorf(ux);
        const int i0 = (int)x0f;
        const int i1 = i0 + 1;
        const float w1 = ux - x0f;
        const float w0 = 1.0f - w1;
        const float aw = ex[p] * inv * wy;
        const float f0 = aw * w0 * ((i0 >= 0 && i0 < L_Q) ? 1.0f : 0.0f);
        const float f1 = aw * w1 * ((i1 >= 0 && i1 < L_Q) ? 1.0f : 0.0f);
        const int i0c = i0 < 0 ? 0 : (i0 > L_Q - 1 ? L_Q - 1 : i0);
        const int i1c = i1 < 0 ? 0 : (i1 > L_Q - 1 ? L_Q - 1 : i1);
        const ushort4 v0 = *(const ushort4*)(vproj + (size_t)(b * L_Q + i0c) * D_MODEL + h * 128 + dd);
        const ushort4 v1 = *(const ushort4*)(vproj + (size_t)(b * L_Q + i1c) * D_MODEL + h * 128 + dd);
        acc0 += f0 * bf2f(v0.x) + f1 * bf2f(v1.x);
        acc1 += f0 * bf2f(v0.y) + f1 * bf2f(v1.y);
        acc2 += f0 * bf2f(v0.z) + f1 * bf2f(v1.z);
        acc3 += f0 * bf2f(v0.w) + f1 * bf2f(v1.w);
    }
    ushort4 o;
    o.x = f2bf(acc0); o.y = f2bf(acc1); o.z = f2bf(acc2); o.w = f2bf(acc3);
    *(ushort4*)(agg + (size_t)row * D_MODEL + t * 4) = o;
}

// ---------------- launch ----------------

extern "C" void kernel_launch(void* const* d_in, const int* in_sizes, int n_in,
                              void* d_out, int out_size, void* d_ws, size_t ws_size,
                              hipStream_t stream) {
    const float* query = (const float*)d_in[0];
    // d_in[1] key_in: unused (dead code in reference)
    const float* value = (const float*)d_in[2];
    // d_in[3] Wqk, d_in[4] bqk: unused (dead code)
    const float* Wv    = (const float*)d_in[5];
    const float* bv    = (const float*)d_in[6];
    const float* Woff  = (const float*)d_in[7];
    const float* boff  = (const float*)d_in[8];
    const float* Wattn = (const float*)d_in[9];
    const float* battn = (const float*)d_in[10];
    const float* Wo    = (const float*)d_in[11];
    const float* bo    = (const float*)d_in[12];

    char* ws = (char*)d_ws;
    size_t off = 0;
    auto alloc = [&](size_t bytes) -> char* {
        char* p = ws + off;
        off += (bytes + 255) & ~(size_t)255;
        return p;
    };
    unsigned short* val_bf = (unsigned short*)alloc((size_t)M_ROWS * D_MODEL * 2);  // 32MB
    unsigned short* qhi    = (unsigned short*)alloc((size_t)M_ROWS * D_MODEL * 2);  // 32MB
    unsigned short* qlo    = (unsigned short*)alloc((size_t)M_ROWS * D_MODEL * 2);  // 32MB
    unsigned short* vproj  = (unsigned short*)alloc((size_t)M_ROWS * D_MODEL * 2);  // 32MB
    unsigned short* agg    = (unsigned short*)alloc((size_t)M_ROWS * D_MODEL * 2);  // 32MB
    float*          C96    = (float*)alloc((size_t)M_ROWS * 96 * 4);                // 6MB
    unsigned short* WvT    = (unsigned short*)alloc((size_t)D_MODEL * D_MODEL * 2); // 2MB
    unsigned short* WoT    = (unsigned short*)alloc((size_t)D_MODEL * D_MODEL * 2); // 2MB
    unsigned short* WcT3   = (unsigned short*)alloc((size_t)96 * 3072 * 2);         // 0.6MB

    const int n4 = M_ROWS * D_MODEL / 4;
    k_cast_value<<<2048, 256, 0, stream>>>(value, val_bf, n4);
    k_split_query<<<2048, 256, 0, stream>>>(query, qhi, qlo, n4);
    k_prep_weights<<<1024, 256, 0, stream>>>(Wv, Wo, Woff, Wattn, WvT, WoT, WcT3);

    // v = value @ Wv + bv   (bf16 out)
    k_gemm256<true><<<256, 512, 0, stream>>>(val_bf, WvT, bv, vproj);

    // C96 = query @ [Woff|Wattn] + [boff|battn]   (fp32-accurate hi/lo, K=3072 concat GEMM)
    k_offattn2<<<M_ROWS / 64, 512, 0, stream>>>(qhi, qlo, WcT3, boff, battn, C96);

    // agg = deformable sample + attn-weighted sum  (bf16 out)
    k_sampler<<<M_ROWS, 256, 0, stream>>>(C96, vproj, agg);

    // out = agg @ Wo + bo   (f32 out)
    k_gemm256<false><<<256, 512, 0, stream>>>(agg, WoT, bo, (float*)d_out);
}

// Round 7
// 152.563 us; speedup vs baseline: 1.4249x; 1.2397x over previous
//
#include <hip/hip_runtime.h>

#define L_Q 4096
#define D_MODEL 1024
#define N_B 4
#define N_H 8
#define N_P 4
#define M_ROWS (N_B * L_Q)   // 16384

typedef float f32x4 __attribute__((ext_vector_type(4)));
typedef __bf16 bf16x8 __attribute__((ext_vector_type(8)));
typedef unsigned short u16x8 __attribute__((ext_vector_type(8)));

__device__ __forceinline__ unsigned short f2bf(float f) {
    unsigned int u = __float_as_uint(f);
    u += 0x7FFFu + ((u >> 16) & 1u);      // round-to-nearest-even
    return (unsigned short)(u >> 16);
}
__device__ __forceinline__ float bf2f(unsigned short s) {
    return __uint_as_float(((unsigned int)s) << 16);
}

// async global->LDS, 16B per lane; LDS dest = wave-uniform base + lane*16
__device__ __forceinline__ void gload_lds16(const void* g, void* l) {
    __builtin_amdgcn_global_load_lds((const __attribute__((address_space(1))) void*)g,
                                     (__attribute__((address_space(3))) void*)l,
                                     16, 0, 0);
}

template <int N> __device__ __forceinline__ void wait_vmc() {
    if constexpr (N == 6)      asm volatile("s_waitcnt vmcnt(6)"  ::: "memory");
    else if constexpr (N == 5) asm volatile("s_waitcnt vmcnt(5)"  ::: "memory");
    else if constexpr (N == 4) asm volatile("s_waitcnt vmcnt(4)"  ::: "memory");
    else                       asm volatile("s_waitcnt vmcnt(0)"  ::: "memory");
}

// ---------------- prep kernels ----------------

__global__ void k_cast_value(const float* __restrict__ in, unsigned short* __restrict__ out, int n4) {
    int i = blockIdx.x * blockDim.x + threadIdx.x;
    const int stride = gridDim.x * blockDim.x;
    for (; i < n4; i += stride) {
        float4 v = ((const float4*)in)[i];
        ushort4 o;
        o.x = f2bf(v.x); o.y = f2bf(v.y); o.z = f2bf(v.z); o.w = f2bf(v.w);
        ((ushort4*)out)[i] = o;
    }
}

// WvT/WoT: (N=1024,K=1024) bf16 transposes.
// WcT2: (96, 2048) rows n = [Wh[n](k=0..1023) | Wl[n](k=0..1023)] hi/lo split of [Woff|Wattn]^T.
__global__ void k_prep_weights(const float* __restrict__ Wv, const float* __restrict__ Wo,
                               const float* __restrict__ Woff, const float* __restrict__ Wattn,
                               unsigned short* __restrict__ WvT, unsigned short* __restrict__ WoT,
                               unsigned short* __restrict__ WcT2) {
    const int n1 = D_MODEL * D_MODEL;
    const int n2 = 2 * n1;
    const int n3 = n2 + 96 * 2048;
    int i = blockIdx.x * blockDim.x + threadIdx.x;
    const int stride = gridDim.x * blockDim.x;
    for (; i < n3; i += stride) {
        if (i < n1) {
            int n = i >> 10, k = i & 1023;
            WvT[i] = f2bf(Wv[k * D_MODEL + n]);
        } else if (i < n2) {
            int j = i - n1;
            int n = j >> 10, k = j & 1023;
            WoT[j] = f2bf(Wo[k * D_MODEL + n]);
        } else {
            int j = i - n2;                 // j = row*2048 + half*1024 + k
            int row = j >> 11;
            int rem = j & 2047;
            int half = rem >> 10;
            int k = rem & 1023;
            float w = (row < 64) ? Woff[k * 64 + row] : Wattn[k * 32 + (row - 64)];
            unsigned short h = f2bf(w);
            WcT2[j] = half ? f2bf(w - bf2f(h)) : h;
        }
    }
}

// ---------------- 256x256 cross-phase-pipelined bf16 MFMA GEMM ----------------
// C = A(M,K)*Bt(N,K)^T + bias.  M=16384, N=K=1024. 512 threads = 8 waves (2M x 4N).
// Per phase: STAGE 1 half-tile -> vmcnt(4) -> BAR -> MFMA(quad p, frags read LAST phase)
// -> ds_reads for quad p+1. MFMA never waits on same-phase LDS reads.
// LDS swizzle: chunk16 ^= (row&7), via inverse-swizzled global source (involution).

template <bool OUT_BF16>
__global__ __launch_bounds__(512, 2) void k_gemm256(const unsigned short* __restrict__ A,
                                                    const unsigned short* __restrict__ Bt,
                                                    const float* __restrict__ bias,
                                                    void* __restrict__ Cout) {
    __shared__ __align__(16) unsigned short lds[2][2][2][8192];  // [mat][set][half][128*64]
    const int tid = threadIdx.x;
    const int w = tid >> 6, lane = tid & 63;
    const int wm = w >> 2, wn = w & 3;

    // XCD-bijective swizzle: 256 blocks = 64(M) x 4(N)
    const int bid = blockIdx.x;
    const int swz = (bid & 7) * 32 + (bid >> 3);
    const int m0 = (swz >> 2) * 256;
    const int n0 = (swz & 3) * 256;

    const int sr = (w << 3) + (lane >> 3);
    const int sc = (lane & 7) ^ ((lane >> 3) & 7);
    const size_t aoff1 = (size_t)(m0 + sr) * 1024 + (size_t)(sc * 8);
    const size_t boff1 = (size_t)(n0 + sr) * 1024 + (size_t)(sc * 8);

    const int fr = lane & 15, kq = lane >> 4;
    const int cs0 = ((kq) ^ (fr & 7)) * 8;
    const int cs1 = ((4 + kq) ^ (fr & 7)) * 8;
    const int arow = (wm * 64 + fr) * 64;
    const int brow = (wn * 32 + fr) * 64;

    f32x4 acc[2][2][4][2];
    const f32x4 zero = {0.f, 0.f, 0.f, 0.f};
#pragma unroll
    for (int qm = 0; qm < 2; ++qm)
#pragma unroll
        for (int qn = 0; qn < 2; ++qn)
#pragma unroll
            for (int i = 0; i < 4; ++i)
#pragma unroll
                for (int j = 0; j < 2; ++j) acc[qm][qn][i][j] = zero;

    bf16x8 af[4][2], bl[2][2], bh[2][2];

#define STAGE(mat, set, half, kt) do {                                                  \
        const unsigned short* g_ = ((mat) ? Bt : A) + ((mat) ? boff1 : aoff1)           \
                                   + (size_t)(half) * 131072 + (size_t)(kt);            \
        unsigned short* d_ = &lds[mat][set][half][0] + w * 512;                         \
        gload_lds16(g_, d_);                                                            \
        gload_lds16(g_ + 65536, d_ + 4096);                                             \
    } while (0)

#define LDA(set, qm) do {                                                               \
        const unsigned short* s_ = &lds[0][set][qm][0];                                 \
        _Pragma("unroll") for (int i = 0; i < 4; ++i) {                                 \
            af[i][0] = *(const bf16x8*)(s_ + arow + i * 1024 + cs0);                    \
            af[i][1] = *(const bf16x8*)(s_ + arow + i * 1024 + cs1);                    \
        }                                                                               \
    } while (0)

#define LDB(dst, set, qn) do {                                                          \
        const unsigned short* s_ = &lds[1][set][qn][0];                                 \
        _Pragma("unroll") for (int j = 0; j < 2; ++j) {                                 \
            dst[j][0] = *(const bf16x8*)(s_ + brow + j * 1024 + cs0);                   \
            dst[j][1] = *(const bf16x8*)(s_ + brow + j * 1024 + cs1);                   \
        }                                                                               \
    } while (0)

#define MM(qm, qn, B_) do {                                                             \
        __builtin_amdgcn_s_setprio(1);                                                  \
        _Pragma("unroll") for (int i = 0; i < 4; ++i)                                   \
        _Pragma("unroll") for (int j = 0; j < 2; ++j)                                   \
        _Pragma("unroll") for (int kk = 0; kk < 2; ++kk)                                \
            acc[qm][qn][i][j] = __builtin_amdgcn_mfma_f32_16x16x32_bf16(                \
                af[i][kk], B_[j][kk], acc[qm][qn][i][j], 0, 0, 0);                      \
        __builtin_amdgcn_s_setprio(0);                                                  \
    } while (0)

#define BAR() do { __builtin_amdgcn_s_barrier(); asm volatile("" ::: "memory"); } while (0)

    // prologue: set0 @ kt=0 (A0,B0,B1,A1 = loads 1-8); pre-read frags for quad (0,0)
    STAGE(0, 0, 0, 0);   // A0s0  loads 1-2
    STAGE(1, 0, 0, 0);   // B0s0  loads 3-4
    STAGE(1, 0, 1, 0);   // B1s0  loads 5-6
    STAGE(0, 0, 1, 0);   // A1s0  loads 7-8
    wait_vmc<4>();       // loads 1-4 (A0s0, B0s0) landed
    BAR();
    LDA(0, 0); LDB(bl, 0, 0);

#pragma unroll 1
    for (int it = 0; it < 8; ++it) {
        const int kt = it * 128;
        // q0: MM(0,0) [prologue/q7 frags]; read bh(set0,h1)
        STAGE(0, 1, 0, kt + 64);
        wait_vmc<4>(); BAR();
        MM(0, 0, bl); LDB(bh, 0, 1);
        // q1: MM(0,1); read af(set0,h1)
        STAGE(1, 1, 0, kt + 64);
        wait_vmc<4>(); BAR();
        MM(0, 1, bh); LDA(0, 1);
        // q2: MM(1,1); no reads
        STAGE(1, 1, 1, kt + 64);
        wait_vmc<6>(); BAR();
        MM(1, 1, bh);
        // q3: MM(1,0); read bl(set1), af(set1,h0)
        STAGE(0, 1, 1, kt + 64);
        wait_vmc<4>(); BAR();
        MM(1, 0, bl); LDB(bl, 1, 0); LDA(1, 0);
        // q4: MM(0,0) set1; read bh(set1,h1)
        STAGE(0, 0, 0, kt + 128);
        wait_vmc<4>(); BAR();
        MM(0, 0, bl); LDB(bh, 1, 1);
        // q5: MM(0,1); read af(set1,h1)
        STAGE(1, 0, 0, kt + 128);
        wait_vmc<4>(); BAR();
        MM(0, 1, bh); LDA(1, 1);
        // q6: MM(1,1); no reads
        STAGE(1, 0, 1, kt + 128);
        wait_vmc<6>(); BAR();
        MM(1, 1, bh);
        // q7: MM(1,0); read bl(next set0), af(next set0,h0)
        STAGE(0, 0, 1, kt + 128);
        wait_vmc<4>(); BAR();
        MM(1, 0, bl); LDB(bl, 0, 0); LDA(0, 0);
    }
    wait_vmc<0>();   // drain tail junk stages

#undef STAGE
#undef LDA
#undef LDB
#undef MM
#undef BAR

#pragma unroll
    for (int qm = 0; qm < 2; ++qm) {
#pragma unroll
        for (int qn = 0; qn < 2; ++qn) {
#pragma unroll
            for (int i = 0; i < 4; ++i) {
#pragma unroll
                for (int j = 0; j < 2; ++j) {
                    const int col = n0 + qn * 128 + wn * 32 + j * 16 + fr;
                    const float bcol = bias[col];
#pragma unroll
                    for (int r = 0; r < 4; ++r) {
                        const int row = m0 + qm * 128 + wm * 64 + i * 16 + kq * 4 + r;
                        const float v = acc[qm][qn][i][j][r] + bcol;
                        if (OUT_BF16)
                            ((unsigned short*)Cout)[(size_t)row * D_MODEL + col] = f2bf(v);
                        else
                            ((float*)Cout)[(size_t)row * D_MODEL + col] = v;
                    }
                }
            }
        }
    }
}

// ---------------- off/attn projection, fused hi/lo split ----------------
// C96(M,96) = qhi*Wh + qhi*Wl + qlo*Wh + bias, computed per K-tile (16 tiles of 64).
// A: reg-staged query f32 -> hi/lo bf16 in regs -> swizzled ds_write (1-tile-ahead prefetch).
// B: gload_lds from stacked WcT2 (LDS rows 0-95 = Wh, 96-191 = Wl). Double-buffered.

__global__ __launch_bounds__(512, 2) void k_offattn2(const float* __restrict__ query,
                                                     const unsigned short* __restrict__ WcT2,
                                                     const float* __restrict__ boff,
                                                     const float* __restrict__ battn,
                                                     float* __restrict__ C96) {
    __shared__ __align__(16) unsigned short ldsA[2][128 * 64];  // rows 0-63 hi, 64-127 lo
    __shared__ __align__(16) unsigned short ldsB[2][192 * 64];  // rows 0-95 Wh, 96-191 Wl
    const int tid = threadIdx.x;
    const int w = tid >> 6, lane = tid & 63;
    const int wm = w >> 1, wn = w & 1;
    const int m0 = blockIdx.x * 64;

    // A source: thread covers (row = tid>>3, chunk = tid&7); 8 consecutive f32
    const int ar = tid >> 3;
    const int ac = tid & 7;
    const float* qbase = query + (size_t)(m0 + ar) * 1024 + ac * 8;
    const int aw_hi = ar * 64 + ((ac ^ (ar & 7)) * 8);          // swizzled write offsets
    const int aw_lo = (64 + ar) * 64 + ((ac ^ (ar & 7)) * 8);

    // B staging: round i (0..2), wave w covers stacked rows i*64+8w .. +7
    const int brl = lane >> 3;
    const int bchk = (lane & 7) ^ (brl & 7);

    // frag read geometry (chunk ^= row&7)
    const int fr = lane & 15, kq = lane >> 4;
    const int cs0 = ((kq) ^ (fr & 7)) * 8;
    const int cs1 = ((4 + kq) ^ (fr & 7)) * 8;
    const int ahr = (wm * 16 + fr) * 64;          // hi rows
    const int alr = (64 + wm * 16 + fr) * 64;     // lo rows

    f32x4 acc[3];
    const f32x4 zero = {0.f, 0.f, 0.f, 0.f};
#pragma unroll
    for (int j = 0; j < 3; ++j) acc[j] = zero;

#define ALOAD(f0_, f1_, kt_) do {                                                       \
        f0_ = *(const float4*)(qbase + (kt_));                                          \
        f1_ = *(const float4*)(qbase + (kt_) + 4);                                      \
    } while (0)

#define BSTAGE(p_, kt_) do {                                                            \
        _Pragma("unroll") for (int i_ = 0; i_ < 3; ++i_) {                              \
            const int sr_ = i_ * 64 + w * 8 + brl;                                      \
            const unsigned short* g_ = WcT2 + ((sr_ < 96)                               \
                    ? ((size_t)sr_ * 2048 + (size_t)(kt_))                              \
                    : ((size_t)(sr_ - 96) * 2048 + 1024 + (size_t)(kt_)))               \
                    + (size_t)(bchk * 8);                                               \
            gload_lds16(g_, &ldsB[p_][(i_ * 64 + w * 8) * 64]);                         \
        }                                                                               \
    } while (0)

#define AWRITE(p_, f0_, f1_) do {                                                       \
        u16x8 hi_, lo_;                                                                 \
        const float vv_[8] = {f0_.x, f0_.y, f0_.z, f0_.w, f1_.x, f1_.y, f1_.z, f1_.w};  \
        _Pragma("unroll") for (int e_ = 0; e_ < 8; ++e_) {                              \
            hi_[e_] = f2bf(vv_[e_]);                                                    \
            lo_[e_] = f2bf(vv_[e_] - bf2f(hi_[e_]));                                    \
        }                                                                               \
        *(u16x8*)(&ldsA[p_][aw_hi]) = hi_;                                              \
        *(u16x8*)(&ldsA[p_][aw_lo]) = lo_;                                              \
    } while (0)

#define OMM(p_) do {                                                                    \
        const unsigned short* As_ = &ldsA[p_][0];                                       \
        const unsigned short* Bs_ = &ldsB[p_][0];                                       \
        bf16x8 ah0 = *(const bf16x8*)(As_ + ahr + cs0);                                 \
        bf16x8 ah1 = *(const bf16x8*)(As_ + ahr + cs1);                                 \
        bf16x8 al0 = *(const bf16x8*)(As_ + alr + cs0);                                 \
        bf16x8 al1 = *(const bf16x8*)(As_ + alr + cs1);                                 \
        __builtin_amdgcn_s_setprio(1);                                                  \
        _Pragma("unroll") for (int j = 0; j < 3; ++j) {                                 \
            const int br_ = (wn * 48 + j * 16 + fr) * 64;                               \
            bf16x8 wh0 = *(const bf16x8*)(Bs_ + br_ + cs0);                             \
            bf16x8 wh1 = *(const bf16x8*)(Bs_ + br_ + cs1);                             \
            bf16x8 wl0 = *(const bf16x8*)(Bs_ + 6144 + br_ + cs0);                      \
            bf16x8 wl1 = *(const bf16x8*)(Bs_ + 6144 + br_ + cs1);                      \
            acc[j] = __builtin_amdgcn_mfma_f32_16x16x32_bf16(ah0, wh0, acc[j], 0, 0, 0);\
            acc[j] = __builtin_amdgcn_mfma_f32_16x16x32_bf16(ah1, wh1, acc[j], 0, 0, 0);\
            acc[j] = __builtin_amdgcn_mfma_f32_16x16x32_bf16(ah0, wl0, acc[j], 0, 0, 0);\
            acc[j] = __builtin_amdgcn_mfma_f32_16x16x32_bf16(ah1, wl1, acc[j], 0, 0, 0);\
            acc[j] = __builtin_amdgcn_mfma_f32_16x16x32_bf16(al0, wh0, acc[j], 0, 0, 0);\
            acc[j] = __builtin_amdgcn_mfma_f32_16x16x32_bf16(al1, wh1, acc[j], 0, 0, 0);\
        }                                                                               \
        __builtin_amdgcn_s_setprio(0);                                                  \
    } while (0)

#define OBODY(t_, p_, fc0_, fc1_, fn0_, fn1_) do {                                      \
        if ((t_) < 15) {                                                                \
            ALOAD(fn0_, fn1_, ((t_) + 1) * 64);                                         \
            BSTAGE((p_) ^ 1, ((t_) + 1) * 64);                                          \
            wait_vmc<5>();                                                              \
        } else {                                                                        \
            wait_vmc<0>();                                                              \
        }                                                                               \
        AWRITE(p_, fc0_, fc1_);                                                         \
        asm volatile("s_waitcnt lgkmcnt(0)" ::: "memory");                              \
        __builtin_amdgcn_s_barrier(); asm volatile("" ::: "memory");                    \
        OMM(p_);                                                                        \
        __builtin_amdgcn_s_barrier(); asm volatile("" ::: "memory");                    \
    } while (0)

    float4 a0A, a1A, a0B, a1B;
    ALOAD(a0A, a1A, 0);
    BSTAGE(0, 0);

#pragma unroll 1
    for (int t2 = 0; t2 < 8; ++t2) {
        const int t = t2 * 2;
        OBODY(t,     0, a0A, a1A, a0B, a1B);
        OBODY(t + 1, 1, a0B, a1B, a0A, a1A);
    }

#undef ALOAD
#undef BSTAGE
#undef AWRITE
#undef OMM
#undef OBODY

#pragma unroll
    for (int j = 0; j < 3; ++j) {
        const int col = wn * 48 + j * 16 + fr;
        const float bcol = (col < 64) ? boff[col] : battn[col - 64];
#pragma unroll
        for (int r = 0; r < 4; ++r) {
            const int row = m0 + wm * 16 + kq * 4 + r;
            C96[(size_t)row * 96 + col] = acc[j][r] + bcol;
        }
    }
}

// ---------------- sampler: softmax + bilinear gather + weighted sum ----------------

__global__ void k_sampler(const float* __restrict__ C96,
                          const unsigned short* __restrict__ vproj,
                          unsigned short* __restrict__ agg) {
    const int row = blockIdx.x;          // b*L + l
    const int b = row >> 12;
    const int l = row & (L_Q - 1);
    const int t = threadIdx.x;

    __shared__ float cv[96];
    if (t < 96) cv[t] = C96[(size_t)row * 96 + t];
    __syncthreads();

    const int h = t >> 5;
    const int dd = (t & 31) * 4;
    const float ref_y = (float)l / 4095.0f;

    float lg[4];
#pragma unroll
    for (int p = 0; p < 4; ++p) lg[p] = cv[64 + h * 4 + p];
    const float mx = fmaxf(fmaxf(lg[0], lg[1]), fmaxf(lg[2], lg[3]));
    float ex[4];
    float es = 0.f;
#pragma unroll
    for (int p = 0; p < 4; ++p) { ex[p] = expf(lg[p] - mx); es += ex[p]; }
    const float inv = 1.0f / es;

    float acc0 = 0.f, acc1 = 0.f, acc2 = 0.f, acc3 = 0.f;
#pragma unroll
    for (int p = 0; p < 4; ++p) {
        const float ox = cv[h * 8 + p * 2];
        const float oy = cv[h * 8 + p * 2 + 1];
        const float lx = fminf(fmaxf(ox, 0.0f), 1.0f);               // ref_x = 0
        const float ly = fminf(fmaxf(ref_y + oy, 0.0f), 1.0f);
        const float ux = (lx + 1.0f) * 2048.0f - 0.5f;               // ((x+1)*L - 1)/2
        const float wy = 1.0f - ly * 0.5f;                           // uy in [0,0.5] -> wy = 1-uy
        const float x0f = floorf(ux);
        const int i0 = (int)x0f;
        const int i1 = i0 + 1;
        const float w1 = ux - x0f;
        const float w0 = 1.0f - w1;
        const float aw = ex[p] * inv * wy;
        const float f0 = aw * w0 * ((i0 >= 0 && i0 < L_Q) ? 1.0f : 0.0f);
        const float f1 = aw * w1 * ((i1 >= 0 && i1 < L_Q) ? 1.0f : 0.0f);
        const int i0c = i0 < 0 ? 0 : (i0 > L_Q - 1 ? L_Q - 1 : i0);
        const int i1c = i1 < 0 ? 0 : (i1 > L_Q - 1 ? L_Q - 1 : i1);
        const ushort4 v0 = *(const ushort4*)(vproj + (size_t)(b * L_Q + i0c) * D_MODEL + h * 128 + dd);
        const ushort4 v1 = *(const ushort4*)(vproj + (size_t)(b * L_Q + i1c) * D_MODEL + h * 128 + dd);
        acc0 += f0 * bf2f(v0.x) + f1 * bf2f(v1.x);
        acc1 += f0 * bf2f(v0.y) + f1 * bf2f(v1.y);
        acc2 += f0 * bf2f(v0.z) + f1 * bf2f(v1.z);
        acc3 += f0 * bf2f(v0.w) + f1 * bf2f(v1.w);
    }
    ushort4 o;
    o.x = f2bf(acc0); o.y = f2bf(acc1); o.z = f2bf(acc2); o.w = f2bf(acc3);
    *(ushort4*)(agg + (size_t)row * D_MODEL + t * 4) = o;
}

// ---------------- launch ----------------

extern "C" void kernel_launch(void* const* d_in, const int* in_sizes, int n_in,
                              void* d_out, int out_size, void* d_ws, size_t ws_size,
                              hipStream_t stream) {
    const float* query = (const float*)d_in[0];
    // d_in[1] key_in: unused (dead code in reference)
    const float* value = (const float*)d_in[2];
    // d_in[3] Wqk, d_in[4] bqk: unused (dead code)
    const float* Wv    = (const float*)d_in[5];
    const float* bv    = (const float*)d_in[6];
    const float* Woff  = (const float*)d_in[7];
    const float* boff  = (const float*)d_in[8];
    const float* Wattn = (const float*)d_in[9];
    const float* battn = (const float*)d_in[10];
    const float* Wo    = (const float*)d_in[11];
    const float* bo    = (const float*)d_in[12];

    char* ws = (char*)d_ws;
    size_t off = 0;
    auto alloc = [&](size_t bytes) -> char* {
        char* p = ws + off;
        off += (bytes + 255) & ~(size_t)255;
        return p;
    };
    unsigned short* val_bf = (unsigned short*)alloc((size_t)M_ROWS * D_MODEL * 2);  // 32MB
    unsigned short* vproj  = (unsigned short*)alloc((size_t)M_ROWS * D_MODEL * 2);  // 32MB
    unsigned short* agg    = (unsigned short*)alloc((size_t)M_ROWS * D_MODEL * 2);  // 32MB
    float*          C96    = (float*)alloc((size_t)M_ROWS * 96 * 4);                // 6MB
    unsigned short* WvT    = (unsigned short*)alloc((size_t)D_MODEL * D_MODEL * 2); // 2MB
    unsigned short* WoT    = (unsigned short*)alloc((size_t)D_MODEL * D_MODEL * 2); // 2MB
    unsigned short* WcT2   = (unsigned short*)alloc((size_t)96 * 2048 * 2);         // 0.4MB

    const int n4 = M_ROWS * D_MODEL / 4;
    k_cast_value<<<2048, 256, 0, stream>>>(value, val_bf, n4);
    k_prep_weights<<<1024, 256, 0, stream>>>(Wv, Wo, Woff, Wattn, WvT, WoT, WcT2);

    // v = value @ Wv + bv   (bf16 out)
    k_gemm256<true><<<256, 512, 0, stream>>>(val_bf, WvT, bv, vproj);

    // C96 = query @ [Woff|Wattn] + [boff|battn]   (fp32-accurate fused hi/lo)
    k_offattn2<<<M_ROWS / 64, 512, 0, stream>>>(query, WcT2, boff, battn, C96);

    // agg = deformable sample + attn-weighted sum  (bf16 out)
    k_sampler<<<M_ROWS, 256, 0, stream>>>(C96, vproj, agg);

    // out = agg @ Wo + bo   (f32 out)
    k_gemm256<false><<<256, 512, 0, stream>>>(agg, WoT, bo, (float*)d_out);
}

// Round 8
// 152.216 us; speedup vs baseline: 1.4281x; 1.0023x over previous
//
#include <hip/hip_runtime.h>

#define L_Q 4096
#define D_MODEL 1024
#define N_B 4
#define N_H 8
#define N_P 4
#define M_ROWS (N_B * L_Q)   // 16384

typedef float f32x4 __attribute__((ext_vector_type(4)));
typedef __bf16 bf16x8 __attribute__((ext_vector_type(8)));
typedef unsigned short u16x8 __attribute__((ext_vector_type(8)));

__device__ __forceinline__ unsigned short f2bf(float f) {
    unsigned int u = __float_as_uint(f);
    u += 0x7FFFu + ((u >> 16) & 1u);      // round-to-nearest-even
    return (unsigned short)(u >> 16);
}
__device__ __forceinline__ float bf2f(unsigned short s) {
    return __uint_as_float(((unsigned int)s) << 16);
}
__device__ __forceinline__ u16x8 cvt8(float4 a, float4 b) {
    u16x8 r;
    r[0] = f2bf(a.x); r[1] = f2bf(a.y); r[2] = f2bf(a.z); r[3] = f2bf(a.w);
    r[4] = f2bf(b.x); r[5] = f2bf(b.y); r[6] = f2bf(b.z); r[7] = f2bf(b.w);
    return r;
}

// async global->LDS, 16B per lane; LDS dest = wave-uniform base + lane*16
__device__ __forceinline__ void gload_lds16(const void* g, void* l) {
    __builtin_amdgcn_global_load_lds((const __attribute__((address_space(1))) void*)g,
                                     (__attribute__((address_space(3))) void*)l,
                                     16, 0, 0);
}

template <int N> __device__ __forceinline__ void wait_vmc() {
    if constexpr (N == 6)      asm volatile("s_waitcnt vmcnt(6)"  ::: "memory");
    else if constexpr (N == 5) asm volatile("s_waitcnt vmcnt(5)"  ::: "memory");
    else if constexpr (N == 4) asm volatile("s_waitcnt vmcnt(4)"  ::: "memory");
    else                       asm volatile("s_waitcnt vmcnt(0)"  ::: "memory");
}

// ---------------- prep kernel ----------------

// WvT/WoT: (N=1024,K=1024) bf16 transposes.
// WcT2: (96, 2048) rows n = [Wh[n](k=0..1023) | Wl[n](k=0..1023)] hi/lo split of [Woff|Wattn]^T.
__global__ void k_prep_weights(const float* __restrict__ Wv, const float* __restrict__ Wo,
                               const float* __restrict__ Woff, const float* __restrict__ Wattn,
                               unsigned short* __restrict__ WvT, unsigned short* __restrict__ WoT,
                               unsigned short* __restrict__ WcT2) {
    const int n1 = D_MODEL * D_MODEL;
    const int n2 = 2 * n1;
    const int n3 = n2 + 96 * 2048;
    int i = blockIdx.x * blockDim.x + threadIdx.x;
    const int stride = gridDim.x * blockDim.x;
    for (; i < n3; i += stride) {
        if (i < n1) {
            int n = i >> 10, k = i & 1023;
            WvT[i] = f2bf(Wv[k * D_MODEL + n]);
        } else if (i < n2) {
            int j = i - n1;
            int n = j >> 10, k = j & 1023;
            WoT[j] = f2bf(Wo[k * D_MODEL + n]);
        } else {
            int j = i - n2;                 // j = row*2048 + half*1024 + k
            int row = j >> 11;
            int rem = j & 2047;
            int half = rem >> 10;
            int k = rem & 1023;
            float w = (row < 64) ? Woff[k * 64 + row] : Wattn[k * 32 + (row - 64)];
            unsigned short h = f2bf(w);
            WcT2[j] = half ? f2bf(w - bf2f(h)) : h;
        }
    }
}

// ---------------- 256x256 cross-phase-pipelined bf16 MFMA GEMM ----------------
// C = A(M,K)*Bt(N,K)^T + bias.  M=16384, N=K=1024. 512 threads = 8 waves (2M x 4N).
// A_F32: A is f32, reg-staged (global->reg, f32->bf16 in regs, swizzled ds_write) -- the
//        cast kernel is fused away. Reg tiles pA/pB alternate: issue at q0/q4 (pA), q3/q7 (pB);
//        write 2 phases later; consume 1 phase after the write. vmcnt ledger verified FIFO.
// !A_F32: A is bf16, staged via gload_lds with inverse-swizzled source (as B always is).
// LDS swizzle: chunk16 ^= (row&7) on write and read.

template <bool A_F32, bool OUT_BF16>
__global__ __launch_bounds__(512, 2) void k_gemm256(const void* __restrict__ Ain,
                                                    const unsigned short* __restrict__ Bt,
                                                    const float* __restrict__ bias,
                                                    void* __restrict__ Cout) {
    __shared__ __align__(16) unsigned short lds[2][2][2][8192];  // [mat][set][half][128*64]
    const int tid = threadIdx.x;
    const int w = tid >> 6, lane = tid & 63;
    const int wm = w >> 2, wn = w & 3;

    // XCD-bijective swizzle: 256 blocks = 64(M) x 4(N)
    const int bid = blockIdx.x;
    const int swz = (bid & 7) * 32 + (bid >> 3);
    const int m0 = (swz >> 2) * 256;
    const int n0 = (swz & 3) * 256;

    // gload_lds staging geometry (inverse-swizzled source)
    const int sr = (w << 3) + (lane >> 3);
    const int sc = (lane & 7) ^ ((lane >> 3) & 7);
    const size_t aoff1 = (size_t)(m0 + sr) * 1024 + (size_t)(sc * 8);
    const size_t boff1 = (size_t)(n0 + sr) * 1024 + (size_t)(sc * 8);
    const unsigned short* Ab = (const unsigned short*)Ain;

    // f32 reg-staging geometry: thread covers half-tile row tid>>2 (0..127), 16 f32 at col (tid&3)*16
    const int frow = tid >> 2;
    const int fcol = (tid & 3) * 16;
    const float* fA = (const float*)Ain + (size_t)(m0 + frow) * 1024 + fcol;
    const int fc0 = fcol >> 3;
    const int awr0 = frow * 64 + ((fc0 ^ (frow & 7)) * 8);
    const int awr1 = frow * 64 + (((fc0 + 1) ^ (frow & 7)) * 8);

    // frag read geometry (chunk ^= row&7)
    const int fr = lane & 15, kq = lane >> 4;
    const int cs0 = ((kq) ^ (fr & 7)) * 8;
    const int cs1 = ((4 + kq) ^ (fr & 7)) * 8;
    const int arow = (wm * 64 + fr) * 64;
    const int brow = (wn * 32 + fr) * 64;

    f32x4 acc[2][2][4][2];
    const f32x4 zero = {0.f, 0.f, 0.f, 0.f};
#pragma unroll
    for (int qm = 0; qm < 2; ++qm)
#pragma unroll
        for (int qn = 0; qn < 2; ++qn)
#pragma unroll
            for (int i = 0; i < 4; ++i)
#pragma unroll
                for (int j = 0; j < 2; ++j) acc[qm][qn][i][j] = zero;

    bf16x8 af[4][2], bl[2][2], bh[2][2];
    float4 pA0, pA1, pA2, pA3, pB0, pB1, pB2, pB3;

#define GSTA(set, half, kt) do {                                                        \
        const unsigned short* g_ = Ab + aoff1 + (size_t)(half) * 131072 + (size_t)(kt); \
        unsigned short* d_ = &lds[0][set][half][0] + w * 512;                           \
        gload_lds16(g_, d_);                                                            \
        gload_lds16(g_ + 65536, d_ + 4096);                                             \
    } while (0)

#define GSTB(set, half, kt) do {                                                        \
        const unsigned short* g_ = Bt + boff1 + (size_t)(half) * 131072 + (size_t)(kt); \
        unsigned short* d_ = &lds[1][set][half][0] + w * 512;                           \
        gload_lds16(g_, d_);                                                            \
        gload_lds16(g_ + 65536, d_ + 4096);                                             \
    } while (0)

#define AISSUE(P_, half, kt) do {                                                       \
        const float* s_ = fA + (size_t)(half) * 131072 + (size_t)(kt);                  \
        P_##0 = *(const float4*)(s_);                                                   \
        P_##1 = *(const float4*)(s_ + 4);                                               \
        P_##2 = *(const float4*)(s_ + 8);                                               \
        P_##3 = *(const float4*)(s_ + 12);                                              \
    } while (0)

#define AWRITE(P_, set, half) do {                                                      \
        *(u16x8*)(&lds[0][set][half][awr0]) = cvt8(P_##0, P_##1);                       \
        *(u16x8*)(&lds[0][set][half][awr1]) = cvt8(P_##2, P_##3);                       \
        asm volatile("s_waitcnt lgkmcnt(0)" ::: "memory");                              \
    } while (0)

#define LDA(set, qm) do {                                                               \
        const unsigned short* s_ = &lds[0][set][qm][0];                                 \
        _Pragma("unroll") for (int i = 0; i < 4; ++i) {                                 \
            af[i][0] = *(const bf16x8*)(s_ + arow + i * 1024 + cs0);                    \
            af[i][1] = *(const bf16x8*)(s_ + arow + i * 1024 + cs1);                    \
        }                                                                               \
    } while (0)

#define LDB(dst, set, qn) do {                                                          \
        const unsigned short* s_ = &lds[1][set][qn][0];                                 \
        _Pragma("unroll") for (int j = 0; j < 2; ++j) {                                 \
            dst[j][0] = *(const bf16x8*)(s_ + brow + j * 1024 + cs0);                   \
            dst[j][1] = *(const bf16x8*)(s_ + brow + j * 1024 + cs1);                   \
        }                                                                               \
    } while (0)

#define MM(qm, qn, B_) do {                                                             \
        __builtin_amdgcn_s_setprio(1);                                                  \
        _Pragma("unroll") for (int i = 0; i < 4; ++i)                                   \
        _Pragma("unroll") for (int j = 0; j < 2; ++j)                                   \
        _Pragma("unroll") for (int kk = 0; kk < 2; ++kk)                                \
            acc[qm][qn][i][j] = __builtin_amdgcn_mfma_f32_16x16x32_bf16(                \
                af[i][kk], B_[j][kk], acc[qm][qn][i][j], 0, 0, 0);                      \
        __builtin_amdgcn_s_setprio(0);                                                  \
    } while (0)

#define BAR() do { __builtin_amdgcn_s_barrier(); asm volatile("" ::: "memory"); } while (0)

    // ---- prologue: set0 @ kt=0 staged, frags for quad (0,0) pre-read ----
    if constexpr (A_F32) {
        AISSUE(pA, 0, 0);     // A0s0 regs       (4 loads)
        GSTB(0, 0, 0);        // B0s0            (2)
        GSTB(0, 1, 0);        // B1s0            (2)
        wait_vmc<4>();        // drain pA
        AWRITE(pA, 0, 0);
        AISSUE(pB, 1, 0);     // A1s0 regs       (4)
        wait_vmc<6>();        // drain B0s0; leaves [B1s0 x2, pB x4]
        BAR();
    } else {
        GSTA(0, 0, 0);        // A0s0
        GSTB(0, 0, 0);        // B0s0
        GSTB(0, 1, 0);        // B1s0
        GSTA(0, 1, 0);        // A1s0
        wait_vmc<4>();        // A0s0, B0s0 landed
        BAR();
    }
    LDA(0, 0); LDB(bl, 0, 0);

#pragma unroll 1
    for (int it = 0; it < 8; ++it) {
        const int kt = it * 128;
        const int ktn = (kt + 128) & 1023;   // wrap junk tail stages in-bounds
        if constexpr (A_F32) {
            // q0: issue pA<-A0s1; write pB->A1s0; vm4 (drains B1s0 + pB)
            AISSUE(pA, 0, kt + 64);
            wait_vmc<4>(); AWRITE(pB, 0, 1); BAR();
            MM(0, 0, bl); LDB(bh, 0, 1);
            // q1: B0s1
            GSTB(1, 0, kt + 64);
            BAR();
            MM(0, 1, bh); LDA(0, 1);
            // q2: B1s1; write pA->A0s1; vm4 (drains pA)
            GSTB(1, 1, kt + 64);
            wait_vmc<4>(); AWRITE(pA, 1, 0); BAR();
            MM(1, 1, bh);
            // q3: issue pB<-A1s1; vm6 (drains B0s1)
            AISSUE(pB, 1, kt + 64);
            wait_vmc<6>(); BAR();
            MM(1, 0, bl); LDB(bl, 1, 0); LDA(1, 0);
            // q4: issue pA<-A0s0'; write pB->A1s1; vm4 (drains B1s1 + pB)
            AISSUE(pA, 0, ktn);
            wait_vmc<4>(); AWRITE(pB, 1, 1); BAR();
            MM(0, 0, bl); LDB(bh, 1, 1);
            // q5: B0s0'
            GSTB(0, 0, ktn);
            BAR();
            MM(0, 1, bh); LDA(1, 1);
            // q6: B1s0'; write pA->A0s0'; vm4 (drains pA)
            GSTB(0, 1, ktn);
            wait_vmc<4>(); AWRITE(pA, 0, 0); BAR();
            MM(1, 1, bh);
            // q7: issue pB<-A1s0'; vm6 (drains B0s0')
            AISSUE(pB, 1, ktn);
            wait_vmc<6>(); BAR();
            MM(1, 0, bl); LDB(bl, 0, 0); LDA(0, 0);
        } else {
            // q0
            GSTA(1, 0, kt + 64);
            wait_vmc<4>(); BAR();
            MM(0, 0, bl); LDB(bh, 0, 1);
            // q1
            GSTB(1, 0, kt + 64);
            wait_vmc<4>(); BAR();
            MM(0, 1, bh); LDA(0, 1);
            // q2
            GSTB(1, 1, kt + 64);
            wait_vmc<6>(); BAR();
            MM(1, 1, bh);
            // q3
            GSTA(1, 1, kt + 64);
            wait_vmc<4>(); BAR();
            MM(1, 0, bl); LDB(bl, 1, 0); LDA(1, 0);
            // q4
            GSTA(0, 0, ktn);
            wait_vmc<4>(); BAR();
            MM(0, 0, bl); LDB(bh, 1, 1);
            // q5
            GSTB(0, 0, ktn);
            wait_vmc<4>(); BAR();
            MM(0, 1, bh); LDA(1, 1);
            // q6
            GSTB(0, 1, ktn);
            wait_vmc<6>(); BAR();
            MM(1, 1, bh);
            // q7
            GSTA(0, 1, ktn);
            wait_vmc<4>(); BAR();
            MM(1, 0, bl); LDB(bl, 0, 0); LDA(0, 0);
        }
    }
    wait_vmc<0>();   // drain tail junk stages

#undef GSTA
#undef GSTB
#undef AISSUE
#undef AWRITE
#undef LDA
#undef LDB
#undef MM
#undef BAR

#pragma unroll
    for (int qm = 0; qm < 2; ++qm) {
#pragma unroll
        for (int qn = 0; qn < 2; ++qn) {
#pragma unroll
            for (int i = 0; i < 4; ++i) {
#pragma unroll
                for (int j = 0; j < 2; ++j) {
                    const int col = n0 + qn * 128 + wn * 32 + j * 16 + fr;
                    const float bcol = bias[col];
#pragma unroll
                    for (int r = 0; r < 4; ++r) {
                        const int row = m0 + qm * 128 + wm * 64 + i * 16 + kq * 4 + r;
                        const float v = acc[qm][qn][i][j][r] + bcol;
                        if (OUT_BF16)
                            ((unsigned short*)Cout)[(size_t)row * D_MODEL + col] = f2bf(v);
                        else
                            ((float*)Cout)[(size_t)row * D_MODEL + col] = v;
                    }
                }
            }
        }
    }
}

// ---------------- off/attn projection, fused hi/lo split ----------------
// C96(M,96) = qhi*Wh + qhi*Wl + qlo*Wh + bias, computed per K-tile (16 tiles of 64).

__global__ __launch_bounds__(512, 2) void k_offattn2(const float* __restrict__ query,
                                                     const unsigned short* __restrict__ WcT2,
                                                     const float* __restrict__ boff,
                                                     const float* __restrict__ battn,
                                                     float* __restrict__ C96) {
    __shared__ __align__(16) unsigned short ldsA[2][128 * 64];  // rows 0-63 hi, 64-127 lo
    __shared__ __align__(16) unsigned short ldsB[2][192 * 64];  // rows 0-95 Wh, 96-191 Wl
    const int tid = threadIdx.x;
    const int w = tid >> 6, lane = tid & 63;
    const int wm = w >> 1, wn = w & 1;
    const int m0 = blockIdx.x * 64;

    const int ar = tid >> 3;
    const int ac = tid & 7;
    const float* qbase = query + (size_t)(m0 + ar) * 1024 + ac * 8;
    const int aw_hi = ar * 64 + ((ac ^ (ar & 7)) * 8);
    const int aw_lo = (64 + ar) * 64 + ((ac ^ (ar & 7)) * 8);

    const int brl = lane >> 3;
    const int bchk = (lane & 7) ^ (brl & 7);

    const int fr = lane & 15, kq = lane >> 4;
    const int cs0 = ((kq) ^ (fr & 7)) * 8;
    const int cs1 = ((4 + kq) ^ (fr & 7)) * 8;
    const int ahr = (wm * 16 + fr) * 64;
    const int alr = (64 + wm * 16 + fr) * 64;

    f32x4 acc[3];
    const f32x4 zero = {0.f, 0.f, 0.f, 0.f};
#pragma unroll
    for (int j = 0; j < 3; ++j) acc[j] = zero;

#define ALOAD(f0_, f1_, kt_) do {                                                       \
        f0_ = *(const float4*)(qbase + (kt_));                                          \
        f1_ = *(const float4*)(qbase + (kt_) + 4);                                      \
    } while (0)

#define BSTAGE(p_, kt_) do {                                                            \
        _Pragma("unroll") for (int i_ = 0; i_ < 3; ++i_) {                              \
            const int sr_ = i_ * 64 + w * 8 + brl;                                      \
            const unsigned short* g_ = WcT2 + ((sr_ < 96)                               \
                    ? ((size_t)sr_ * 2048 + (size_t)(kt_))                              \
                    : ((size_t)(sr_ - 96) * 2048 + 1024 + (size_t)(kt_)))               \
                    + (size_t)(bchk * 8);                                               \
            gload_lds16(g_, &ldsB[p_][(i_ * 64 + w * 8) * 64]);                         \
        }                                                                               \
    } while (0)

#define AWRITE2(p_, f0_, f1_) do {                                                      \
        u16x8 hi_, lo_;                                                                 \
        const float vv_[8] = {f0_.x, f0_.y, f0_.z, f0_.w, f1_.x, f1_.y, f1_.z, f1_.w};  \
        _Pragma("unroll") for (int e_ = 0; e_ < 8; ++e_) {                              \
            hi_[e_] = f2bf(vv_[e_]);                                                    \
            lo_[e_] = f2bf(vv_[e_] - bf2f(hi_[e_]));                                    \
        }                                                                               \
        *(u16x8*)(&ldsA[p_][aw_hi]) = hi_;                                              \
        *(u16x8*)(&ldsA[p_][aw_lo]) = lo_;                                              \
    } while (0)

#define OMM(p_) do {                                                                    \
        const unsigned short* As_ = &ldsA[p_][0];                                       \
        const unsigned short* Bs_ = &ldsB[p_][0];                                       \
        bf16x8 ah0 = *(const bf16x8*)(As_ + ahr + cs0);                                 \
        bf16x8 ah1 = *(const bf16x8*)(As_ + ahr + cs1);                                 \
        bf16x8 al0 = *(const bf16x8*)(As_ + alr + cs0);                                 \
        bf16x8 al1 = *(const bf16x8*)(As_ + alr + cs1);                                 \
        __builtin_amdgcn_s_setprio(1);                                                  \
        _Pragma("unroll") for (int j = 0; j < 3; ++j) {                                 \
            const int br_ = (wn * 48 + j * 16 + fr) * 64;                               \
            bf16x8 wh0 = *(const bf16x8*)(Bs_ + br_ + cs0);                             \
            bf16x8 wh1 = *(const bf16x8*)(Bs_ + br_ + cs1);                             \
            bf16x8 wl0 = *(const bf16x8*)(Bs_ + 6144 + br_ + cs0);                      \
            bf16x8 wl1 = *(const bf16x8*)(Bs_ + 6144 + br_ + cs1);                      \
            acc[j] = __builtin_amdgcn_mfma_f32_16x16x32_bf16(ah0, wh0, acc[j], 0, 0, 0);\
            acc[j] = __builtin_amdgcn_mfma_f32_16x16x32_bf16(ah1, wh1, acc[j], 0, 0, 0);\
            acc[j] = __builtin_amdgcn_mfma_f32_16x16x32_bf16(ah0, wl0, acc[j], 0, 0, 0);\
            acc[j] = __builtin_amdgcn_mfma_f32_16x16x32_bf16(ah1, wl1, acc[j], 0, 0, 0);\
            acc[j] = __builtin_amdgcn_mfma_f32_16x16x32_bf16(al0, wh0, acc[j], 0, 0, 0);\
            acc[j] = __builtin_amdgcn_mfma_f32_16x16x32_bf16(al1, wh1, acc[j], 0, 0, 0);\
        }                                                                               \
        __builtin_amdgcn_s_setprio(0);                                                  \
    } while (0)

#define OBODY(t_, p_, fc0_, fc1_, fn0_, fn1_) do {                                      \
        if ((t_) < 15) {                                                                \
            ALOAD(fn0_, fn1_, ((t_) + 1) * 64);                                         \
            BSTAGE((p_) ^ 1, ((t_) + 1) * 64);                                          \
            wait_vmc<5>();                                                              \
        } else {                                                                        \
            wait_vmc<0>();                                                              \
        }                                                                               \
        AWRITE2(p_, fc0_, fc1_);                                                        \
        asm volatile("s_waitcnt lgkmcnt(0)" ::: "memory");                              \
        __builtin_amdgcn_s_barrier(); asm volatile("" ::: "memory");                    \
        OMM(p_);                                                                        \
        __builtin_amdgcn_s_barrier(); asm volatile("" ::: "memory");                    \
    } while (0)

    float4 a0A, a1A, a0B, a1B;
    ALOAD(a0A, a1A, 0);
    BSTAGE(0, 0);

#pragma unroll 1
    for (int t2 = 0; t2 < 8; ++t2) {
        const int t = t2 * 2;
        OBODY(t,     0, a0A, a1A, a0B, a1B);
        OBODY(t + 1, 1, a0B, a1B, a0A, a1A);
    }

#undef ALOAD
#undef BSTAGE
#undef AWRITE2
#undef OMM
#undef OBODY

#pragma unroll
    for (int j = 0; j < 3; ++j) {
        const int col = wn * 48 + j * 16 + fr;
        const float bcol = (col < 64) ? boff[col] : battn[col - 64];
#pragma unroll
        for (int r = 0; r < 4; ++r) {
            const int row = m0 + wm * 16 + kq * 4 + r;
            C96[(size_t)row * 96 + col] = acc[j][r] + bcol;
        }
    }
}

// ---------------- sampler: softmax + bilinear gather + weighted sum ----------------

__global__ void k_sampler(const float* __restrict__ C96,
                          const unsigned short* __restrict__ vproj,
                          unsigned short* __restrict__ agg) {
    const int row = blockIdx.x;          // b*L + l
    const int b = row >> 12;
    const int l = row & (L_Q - 1);
    const int t = threadIdx.x;

    __shared__ float cv[96];
    if (t < 96) cv[t] = C96[(size_t)row * 96 + t];
    __syncthreads();

    const int h = t >> 5;
    const int dd = (t & 31) * 4;
    const float ref_y = (float)l / 4095.0f;

    float lg[4];
#pragma unroll
    for (int p = 0; p < 4; ++p) lg[p] = cv[64 + h * 4 + p];
    const float mx = fmaxf(fmaxf(lg[0], lg[1]), fmaxf(lg[2], lg[3]));
    float ex[4];
    float es = 0.f;
#pragma unroll
    for (int p = 0; p < 4; ++p) { ex[p] = expf(lg[p] - mx); es += ex[p]; }
    const float inv = 1.0f / es;

    float acc0 = 0.f, acc1 = 0.f, acc2 = 0.f, acc3 = 0.f;
#pragma unroll
    for (int p = 0; p < 4; ++p) {
        const float ox = cv[h * 8 + p * 2];
        const float oy = cv[h * 8 + p * 2 + 1];
        const float lx = fminf(fmaxf(ox, 0.0f), 1.0f);               // ref_x = 0
        const float ly = fminf(fmaxf(ref_y + oy, 0.0f), 1.0f);
        const float ux = (lx + 1.0f) * 2048.0f - 0.5f;               // ((x+1)*L - 1)/2
        const float wy = 1.0f - ly * 0.5f;                           // uy in [0,0.5] -> wy = 1-uy
        const float x0f = floorf(ux);
        const int i0 = (int)x0f;
        const int i1 = i0 + 1;
        const float w1 = ux - x0f;
        const float w0 = 1.0f - w1;
        const float aw = ex[p] * inv * wy;
        const float f0 = aw * w0 * ((i0 >= 0 && i0 < L_Q) ? 1.0f : 0.0f);
        const float f1 = aw * w1 * ((i1 >= 0 && i1 < L_Q) ? 1.0f : 0.0f);
        const int i0c = i0 < 0 ? 0 : (i0 > L_Q - 1 ? L_Q - 1 : i0);
        const int i1c = i1 < 0 ? 0 : (i1 > L_Q - 1 ? L_Q - 1 : i1);
        const ushort4 v0 = *(const ushort4*)(vproj + (size_t)(b * L_Q + i0c) * D_MODEL + h * 128 + dd);
        const ushort4 v1 = *(const ushort4*)(vproj + (size_t)(b * L_Q + i1c) * D_MODEL + h * 128 + dd);
        acc0 += f0 * bf2f(v0.x) + f1 * bf2f(v1.x);
        acc1 += f0 * bf2f(v0.y) + f1 * bf2f(v1.y);
        acc2 += f0 * bf2f(v0.z) + f1 * bf2f(v1.z);
        acc3 += f0 * bf2f(v0.w) + f1 * bf2f(v1.w);
    }
    ushort4 o;
    o.x = f2bf(acc0); o.y = f2bf(acc1); o.z = f2bf(acc2); o.w = f2bf(acc3);
    *(ushort4*)(agg + (size_t)row * D_MODEL + t * 4) = o;
}

// ---------------- launch ----------------

extern "C" void kernel_launch(void* const* d_in, const int* in_sizes, int n_in,
                              void* d_out, int out_size, void* d_ws, size_t ws_size,
                              hipStream_t stream) {
    const float* query = (const float*)d_in[0];
    // d_in[1] key_in: unused (dead code in reference)
    const float* value = (const float*)d_in[2];
    // d_in[3] Wqk, d_in[4] bqk: unused (dead code)
    const float* Wv    = (const float*)d_in[5];
    const float* bv    = (const float*)d_in[6];
    const float* Woff  = (const float*)d_in[7];
    const float* boff  = (const float*)d_in[8];
    const float* Wattn = (const float*)d_in[9];
    const float* battn = (const float*)d_in[10];
    const float* Wo    = (const float*)d_in[11];
    const float* bo    = (const float*)d_in[12];

    char* ws = (char*)d_ws;
    size_t off = 0;
    auto alloc = [&](size_t bytes) -> char* {
        char* p = ws + off;
        off += (bytes + 255) & ~(size_t)255;
        return p;
    };
    unsigned short* vproj  = (unsigned short*)alloc((size_t)M_ROWS * D_MODEL * 2);  // 32MB
    unsigned short* agg    = (unsigned short*)alloc((size_t)M_ROWS * D_MODEL * 2);  // 32MB
    float*          C96    = (float*)alloc((size_t)M_ROWS * 96 * 4);                // 6MB
    unsigned short* WvT    = (unsigned short*)alloc((size_t)D_MODEL * D_MODEL * 2); // 2MB
    unsigned short* WoT    = (unsigned short*)alloc((size_t)D_MODEL * D_MODEL * 2); // 2MB
    unsigned short* WcT2   = (unsigned short*)alloc((size_t)96 * 2048 * 2);         // 0.4MB

    k_prep_weights<<<1024, 256, 0, stream>>>(Wv, Wo, Woff, Wattn, WvT, WoT, WcT2);

    // v = value @ Wv + bv   (f32 A reg-staged with fused bf16 cast; bf16 out)
    k_gemm256<true, true><<<256, 512, 0, stream>>>(value, WvT, bv, vproj);

    // C96 = query @ [Woff|Wattn] + [boff|battn]   (fp32-accurate fused hi/lo)
    k_offattn2<<<M_ROWS / 64, 512, 0, stream>>>(query, WcT2, boff, battn, C96);

    // agg = deformable sample + attn-weighted sum  (bf16 out)
    k_sampler<<<M_ROWS, 256, 0, stream>>>(C96, vproj, agg);

    // out = agg @ Wo + bo   (bf16 A via gload_lds; f32 out)
    k_gemm256<false, false><<<256, 512, 0, stream>>>(agg, WoT, bo, (float*)d_out);
}